// Round 9
// baseline (742.161 us; speedup 1.0000x reference)
//
#include <hip/hip_runtime.h>

#define NNODES 262144
#define NEDGES 1048576
#define NB     4096

// ---------------------------------------------------------------------------
// Embedding GEMM fused with v1-dot:
// epart[m, by] = sum_{j in block-y cols} relu(smiles[m]@W1[:,j] + b1[j]) * v1[j]
// tile 64x64, BK=16, 256 threads, 4x4 per thread. M=4096, N=1024, K=768.
// ---------------------------------------------------------------------------
__global__ __launch_bounds__(256) void emb_dot(
    const float* __restrict__ A, const float* __restrict__ B,
    const float* __restrict__ bias, const float* __restrict__ v1,
    float* __restrict__ epart)
{
    __shared__ float As[16][64];
    __shared__ float Bs[16][64];
    __shared__ float red[64][16];
    const int tid = threadIdx.x;
    const int tx = tid & 15, ty = tid >> 4;
    const int m0 = blockIdx.x * 64;
    const int n0 = blockIdx.y * 64;

    float acc[4][4] = {};
    const int ar = tid >> 2, aseg = tid & 3;
    const int bk = tid >> 4, bseg = tid & 15;
    const float* Aptr = A + (size_t)(m0 + ar) * 768 + aseg * 4;
    const float* Bptr = B + (size_t)bk * 1024 + n0 + bseg * 4;

    for (int k0 = 0; k0 < 768; k0 += 16) {
        float4 av = *(const float4*)(Aptr + k0);
        float4 bv = *(const float4*)(Bptr + (size_t)k0 * 1024);
        __syncthreads();
        As[aseg * 4 + 0][ar] = av.x;
        As[aseg * 4 + 1][ar] = av.y;
        As[aseg * 4 + 2][ar] = av.z;
        As[aseg * 4 + 3][ar] = av.w;
        *(float4*)&Bs[bk][bseg * 4] = bv;
        __syncthreads();
#pragma unroll
        for (int k = 0; k < 16; ++k) {
            float4 a4 = *(const float4*)&As[k][ty * 4];
            float4 b4 = *(const float4*)&Bs[k][tx * 4];
            float aa[4] = {a4.x, a4.y, a4.z, a4.w};
            float bb[4] = {b4.x, b4.y, b4.z, b4.w};
#pragma unroll
            for (int i = 0; i < 4; ++i)
#pragma unroll
                for (int j = 0; j < 4; ++j)
                    acc[i][j] += aa[i] * bb[j];
        }
    }

    float4 bb4 = *(const float4*)&bias[n0 + tx * 4];
    float4 vv4 = *(const float4*)&v1[n0 + tx * 4];
#pragma unroll
    for (int i = 0; i < 4; ++i) {
        float p = fmaxf(acc[i][0] + bb4.x, 0.f) * vv4.x
                + fmaxf(acc[i][1] + bb4.y, 0.f) * vv4.y
                + fmaxf(acc[i][2] + bb4.z, 0.f) * vv4.z
                + fmaxf(acc[i][3] + bb4.w, 0.f) * vv4.w;
        red[ty * 4 + i][tx] = p;
    }
    __syncthreads();
    if (tid < 64) {
        float s = 0.f;
#pragma unroll
        for (int c = 0; c < 16; ++c) s += red[tid][c];
        epart[(size_t)(m0 + tid) * 16 + blockIdx.y] = s;
    }
}

// ---------------------------------------------------------------------------
// In-place-safe tiled GEMM (no __restrict__ on A/C): C = relu(A@B + bias)
// A,C: [M,64], B: [64,64]. Each block touches only its own 64 rows; all A
// reads complete (barrier + LDS data dep) before any C store.
// ---------------------------------------------------------------------------
__global__ __launch_bounds__(256) void gemm_ip(
    const float* A, const float* __restrict__ B,
    const float* __restrict__ bias, float* C)
{
    __shared__ float As[16][64];
    __shared__ float Bs[16][64];
    const int tid = threadIdx.x;
    const int tx = tid & 15, ty = tid >> 4;
    const int m0 = blockIdx.x * 64;

    float acc[4][4] = {};
    const int ar = tid >> 2, aseg = tid & 3;
    const int bk = tid >> 4, bseg = tid & 15;
    const float* Aptr = A + (size_t)(m0 + ar) * 64 + aseg * 4;
    const float* Bptr = B + (size_t)bk * 64 + bseg * 4;

    for (int k0 = 0; k0 < 64; k0 += 16) {
        float4 av = *(const float4*)(Aptr + k0);
        float4 bv = *(const float4*)(Bptr + (size_t)k0 * 64);
        __syncthreads();
        As[aseg * 4 + 0][ar] = av.x;
        As[aseg * 4 + 1][ar] = av.y;
        As[aseg * 4 + 2][ar] = av.z;
        As[aseg * 4 + 3][ar] = av.w;
        *(float4*)&Bs[bk][bseg * 4] = bv;
        __syncthreads();
#pragma unroll
        for (int k = 0; k < 16; ++k) {
            float4 a4 = *(const float4*)&As[k][ty * 4];
            float4 b4 = *(const float4*)&Bs[k][tx * 4];
            float aa[4] = {a4.x, a4.y, a4.z, a4.w};
            float bb[4] = {b4.x, b4.y, b4.z, b4.w};
#pragma unroll
            for (int i = 0; i < 4; ++i)
#pragma unroll
                for (int j = 0; j < 4; ++j)
                    acc[i][j] += aa[i] * bb[j];
        }
    }

    float4 b4 = *(const float4*)&bias[tx * 4];
    float bb[4] = {b4.x, b4.y, b4.z, b4.w};
#pragma unroll
    for (int i = 0; i < 4; ++i) {
        float4 v;
        float* vv = (float*)&v;
#pragma unroll
        for (int j = 0; j < 4; ++j)
            vv[j] = fmaxf(acc[i][j] + bb[j], 0.f);
        *(float4*)&C[(size_t)(m0 + ty * 4 + i) * 64 + tx * 4] = v;
    }
}

// ---------------------------------------------------------------------------
// CSR build
// ---------------------------------------------------------------------------
__global__ void count_deg(const int* __restrict__ dst, int* __restrict__ deg)
{
    int i = blockIdx.x * 256 + threadIdx.x;
    if (i < NEDGES) atomicAdd(&deg[dst[i]], 1);
}

__global__ void make_dinv(const int* __restrict__ deg, float* __restrict__ dinv)
{
    int i = blockIdx.x * 256 + threadIdx.x;
    if (i < NNODES) dinv[i] = rsqrtf((float)(deg[i] + 1));   // +1 self loop
}

__global__ __launch_bounds__(1024) void scan_block(
    const int* __restrict__ in, int* __restrict__ out, int* __restrict__ bsums)
{
    __shared__ int tmp[1024];
    const int tid = threadIdx.x;
    const int gid = blockIdx.x * 1024 + tid;
    int v = in[gid];
    tmp[tid] = v;
    __syncthreads();
    for (int off = 1; off < 1024; off <<= 1) {
        int t = (tid >= off) ? tmp[tid - off] : 0;
        __syncthreads();
        tmp[tid] += t;
        __syncthreads();
    }
    out[gid] = tmp[tid] - v;                 // exclusive
    if (tid == 1023) bsums[blockIdx.x] = tmp[tid];
}

__global__ __launch_bounds__(256) void scan_top(int* __restrict__ bsums)
{
    __shared__ int tmp[256];
    const int tid = threadIdx.x;
    int v = bsums[tid];
    tmp[tid] = v;
    __syncthreads();
    for (int off = 1; off < 256; off <<= 1) {
        int t = (tid >= off) ? tmp[tid - off] : 0;
        __syncthreads();
        tmp[tid] += t;
        __syncthreads();
    }
    bsums[tid] = tmp[tid] - v;
}

__global__ void scan_add(int* __restrict__ out, const int* __restrict__ bsums)
{
    int gid = blockIdx.x * 256 + threadIdx.x;
    out[gid] += bsums[gid >> 10];
}

__global__ void scatter_edges(const int* __restrict__ src, const int* __restrict__ dst,
                              int* __restrict__ cur, int* __restrict__ csr)
{
    int i = blockIdx.x * 256 + threadIdx.x;
    if (i < NEDGES) {
        int d = dst[i];
        int pos = atomicAdd(&cur[d], 1);
        csr[pos] = src[i];
    }
}

// ---------------------------------------------------------------------------
// Aggregation: wave per node, lane = feature (64-dim). No float atomics.
// out[i] = sum_{s in N(i)} h[s]*dinv[s]*dinv[i] + h[i]*dinv[i]^2
// ---------------------------------------------------------------------------
__global__ __launch_bounds__(256) void agg_plain(
    const float* __restrict__ h, const int* __restrict__ offs,
    const int* __restrict__ csr, const float* __restrict__ dinv,
    float* __restrict__ out)
{
    const int wid = (blockIdx.x * 256 + threadIdx.x) >> 6;
    const int lane = threadIdx.x & 63;
    if (wid >= NNODES) return;
    const float di = dinv[wid];
    float acc = h[(size_t)wid * 64 + lane] * di * di;
    const int e0 = offs[wid];
    const int e1 = (wid + 1 < NNODES) ? offs[wid + 1] : NEDGES;
    for (int e = e0; e < e1; ++e) {
        int s = csr[e];
        acc += h[(size_t)s * 64 + lane] * (dinv[s] * di);
    }
    out[(size_t)wid * 64 + lane] = acc;
}

// Aggregation fused with mean-pool: u[batch[i]] += agg_row(i) / cnt[batch[i]]
__global__ __launch_bounds__(256) void agg_pool_atomic(
    const float* __restrict__ h, const int* __restrict__ offs,
    const int* __restrict__ csr, const float* __restrict__ dinv,
    const int* __restrict__ bvec, const float* __restrict__ cntinv,
    float* __restrict__ u)
{
    const int wid = (blockIdx.x * 256 + threadIdx.x) >> 6;
    const int lane = threadIdx.x & 63;
    if (wid >= NNODES) return;
    const float di = dinv[wid];
    float acc = h[(size_t)wid * 64 + lane] * di * di;
    const int e0 = offs[wid];
    const int e1 = (wid + 1 < NNODES) ? offs[wid + 1] : NEDGES;
    for (int e = e0; e < e1; ++e) {
        int s = csr[e];
        acc += h[(size_t)s * 64 + lane] * (dinv[s] * di);
    }
    const int g = bvec[wid];
    atomicAdd(&u[(size_t)g * 64 + lane], acc * cntinv[g]);
}

// ---------------------------------------------------------------------------
// Graph segment boundaries (batch_vec is sorted) + inverse counts
// ---------------------------------------------------------------------------
__global__ void graph_starts(const int* __restrict__ bv, int* __restrict__ start)
{
    int g = blockIdx.x * 256 + threadIdx.x;
    if (g > NB) return;
    if (g == NB) { start[g] = NNODES; return; }
    int lo = 0, hi = NNODES;
    while (lo < hi) {
        int mid = (lo + hi) >> 1;
        if (bv[mid] < g) lo = mid + 1; else hi = mid;
    }
    start[g] = lo;
}

__global__ void make_cntinv(const int* __restrict__ start, float* __restrict__ cntinv)
{
    int g = blockIdx.x * 256 + threadIdx.x;
    if (g < NB) cntinv[g] = 1.0f / fmaxf((float)(start[g + 1] - start[g]), 1.0f);
}

// ---------------------------------------------------------------------------
// Precompute folded weight vectors (everything after `combined` is affine).
// wfinal[128] = v_w @ o_w @ f1_w @ ff_w ; split wf1=wfinal[0:64], wf2=[64:128]
// v1[1024] = emb_w2 @ wf1 ; v2[64] = g2_w @ (gfc_w @ wf2)
// c0 = emb_b2.wf1 + g2_b.q1 + gfc_b.wf2 + v_b.p2 + o_b.p1 + f1_b.ff_w + ff_b
// pre layout (floats): [0:128) p1, [128:256) p2, [256:384) wfinal,
//                      [384:512) q1, [512:576) v2, [576:1600) v1, [1600] c0
// ---------------------------------------------------------------------------
__global__ __launch_bounds__(256) void precompute(
    const float* __restrict__ emb_w2, const float* __restrict__ emb_b2,
    const float* __restrict__ g2_w, const float* __restrict__ g2_b,
    const float* __restrict__ gfc_w, const float* __restrict__ gfc_b,
    const float* __restrict__ v_b,
    const float* __restrict__ o_w, const float* __restrict__ o_b,
    const float* __restrict__ f1_w, const float* __restrict__ f1_b,
    const float* __restrict__ ff_w, const float* __restrict__ ff_b,
    const float* __restrict__ v_w, float* __restrict__ pre)
{
    const int tid = threadIdx.x;
    float* p1 = pre;           // [128]
    float* p2 = pre + 128;     // [128]
    float* wf = pre + 256;     // [128]
    float* q1 = pre + 384;     // [128]
    float* v2 = pre + 512;     // [64]
    float* v1 = pre + 576;     // [1024]

    if (tid < 128) {                         // p1 = f1_w @ ff_w
        float s = 0.f;
        for (int k = 0; k < 64; ++k) s += f1_w[tid * 64 + k] * ff_w[k];
        p1[tid] = s;
    }
    __syncthreads();
    if (tid < 128) {                         // p2 = o_w @ p1
        float s = 0.f;
        for (int k = 0; k < 128; ++k) s += o_w[tid * 128 + k] * p1[k];
        p2[tid] = s;
    }
    __syncthreads();
    if (tid < 128) {                         // wfinal = v_w @ p2
        float s = 0.f;
        for (int k = 0; k < 128; ++k) s += v_w[tid * 128 + k] * p2[k];
        wf[tid] = s;
    }
    __syncthreads();
    if (tid < 128) {                         // q1 = gfc_w @ wf2
        float s = 0.f;
        for (int k = 0; k < 64; ++k) s += gfc_w[tid * 64 + k] * wf[64 + k];
        q1[tid] = s;
    }
    __syncthreads();
    if (tid < 64) {                          // v2 = g2_w @ q1
        float s = 0.f;
        for (int k = 0; k < 128; ++k) s += g2_w[tid * 128 + k] * q1[k];
        v2[tid] = s;
    }
    for (int r = 0; r < 4; ++r) {            // v1 = emb_w2 @ wf1
        int j = tid + 256 * r;
        float s = 0.f;
        for (int k = 0; k < 64; ++k) s += emb_w2[j * 64 + k] * wf[k];
        v1[j] = s;
    }
    if (tid == 0) {                          // c0 (all bias-chain dots)
        float c = ff_b[0];
        for (int k = 0; k < 64; ++k)  c += f1_b[k] * ff_w[k];
        for (int i = 0; i < 128; ++i) c += o_b[i] * p1[i] + v_b[i] * p2[i];
        for (int k = 0; k < 64; ++k)  c += emb_b2[k] * wf[k];
        for (int i = 0; i < 128; ++i) c += g2_b[i] * q1[i];
        for (int k = 0; k < 64; ++k)  c += gfc_b[k] * wf[64 + k];
        pre[1600] = c;
    }
}

// out[b] = sum_c epart[b,c] + u[b].v2 + c0
__global__ void final_combine(
    const float* __restrict__ epart, const float* __restrict__ u,
    const float* __restrict__ pre, float* __restrict__ out)
{
    int b = blockIdx.x * 256 + threadIdx.x;
    if (b >= NB) return;
    float s = pre[1600];
    const float* ep = &epart[(size_t)b * 16];
#pragma unroll
    for (int c = 0; c < 16; ++c) s += ep[c];
    const float* ub = &u[(size_t)b * 64];
    const float* v2 = pre + 512;
    for (int k = 0; k < 64; ++k) s += ub[k] * v2[k];
    out[b] = s;
}

// ---------------------------------------------------------------------------
extern "C" void kernel_launch(void* const* d_in, const int* in_sizes, int n_in,
                              void* d_out, int out_size, void* d_ws, size_t ws_size,
                              hipStream_t stream)
{
    const float* smiles = (const float*)d_in[0];    // [4096,1,768]
    const float* node_x = (const float*)d_in[1];    // [262144,64]
    const int*   esrc   = (const int*)d_in[2];
    const int*   edst   = (const int*)d_in[3];
    const int*   bvec   = (const int*)d_in[4];      // sorted
    const float* emb_w1 = (const float*)d_in[5];    // [768,1024]
    const float* emb_b1 = (const float*)d_in[6];
    const float* emb_w2 = (const float*)d_in[7];    // [1024,64]
    const float* emb_b2 = (const float*)d_in[8];
    const float* g1_w   = (const float*)d_in[9];    // [64,64]
    const float* g1_b   = (const float*)d_in[10];
    const float* g2_w   = (const float*)d_in[11];   // [64,128]
    const float* g2_b   = (const float*)d_in[12];
    const float* gfc_w  = (const float*)d_in[13];   // [128,64]
    const float* gfc_b  = (const float*)d_in[14];
    // q_w/q_b/k_w/k_b (15..18) dead: S=1 collapses top-k softmax to identity
    const float* v_w    = (const float*)d_in[19];   // [128,128]
    const float* v_b    = (const float*)d_in[20];
    const float* o_w    = (const float*)d_in[21];   // [128,128]
    const float* o_b    = (const float*)d_in[22];
    const float* f1_w   = (const float*)d_in[23];   // [128,64]
    const float* f1_b   = (const float*)d_in[24];
    const float* ff_w   = (const float*)d_in[25];   // [64,1]
    const float* ff_b   = (const float*)d_in[26];   // [1]
    float* out = (float*)d_out;

    // workspace carve-up (total ~74 MB)
    char* ws = (char*)d_ws;
    size_t off = 0;
    auto alloc = [&](size_t b) -> void* {
        void* p = ws + off;
        off += (b + 255) & ~(size_t)255;
        return p;
    };
    float* buf    = (float*)alloc((size_t)NNODES * 64 * 4);   // 64 MB, the only N-buffer
    int*   deg    = (int*)alloc((size_t)NNODES * 4);
    int*   offs   = (int*)alloc((size_t)NNODES * 4);
    int*   cur    = (int*)alloc((size_t)NNODES * 4);
    float* dinv   = (float*)alloc((size_t)NNODES * 4);
    int*   csr    = (int*)alloc((size_t)NEDGES * 4);
    int*   startg = (int*)alloc((size_t)(NB + 1) * 4);
    int*   bsums  = (int*)alloc(256 * 4);
    float* cntinv = (float*)alloc((size_t)NB * 4);
    float* epart  = (float*)alloc((size_t)NB * 16 * 4);
    float* u      = (float*)alloc((size_t)NB * 64 * 4);
    float* pre    = (float*)alloc(2048 * 4);

    // ---- CSR build (int atomics only) ----
    hipMemsetAsync(deg, 0, (size_t)NNODES * 4, stream);
    hipMemsetAsync(u, 0, (size_t)NB * 64 * 4, stream);
    count_deg<<<NEDGES / 256, 256, 0, stream>>>(edst, deg);
    make_dinv<<<NNODES / 256, 256, 0, stream>>>(deg, dinv);
    scan_block<<<NNODES / 1024, 1024, 0, stream>>>(deg, offs, bsums);
    scan_top<<<1, 256, 0, stream>>>(bsums);
    scan_add<<<NNODES / 256, 256, 0, stream>>>(offs, bsums);
    hipMemcpyAsync(cur, offs, (size_t)NNODES * 4, hipMemcpyDeviceToDevice, stream);
    scatter_edges<<<NEDGES / 256, 256, 0, stream>>>(esrc, edst, cur, csr);
    graph_starts<<<(NB + 256) / 256, 256, 0, stream>>>(bvec, startg);
    make_cntinv<<<NB / 256, 256, 0, stream>>>(startg, cntinv);

    // ---- folded tail weights ----
    precompute<<<1, 256, 0, stream>>>(emb_w2, emb_b2, g2_w, g2_b, gfc_w, gfc_b,
                                      v_b, o_w, o_b, f1_w, f1_b, ff_w, ff_b,
                                      v_w, pre);

    // ---- embedding branch: relu(smiles@W1+b1) . v1 -> epart[B,16] ----
    emb_dot<<<dim3(NB / 64, 16), 256, 0, stream>>>(smiles, emb_w1, emb_b1,
                                                   pre + 576, epart);

    // ---- GCN branch: u = M . A_hat . relu((A_hat X) @ g1_w + b1) ----
    agg_plain<<<NNODES / 4, 256, 0, stream>>>(node_x, offs, csr, dinv, buf);
    gemm_ip<<<NNODES / 64, 256, 0, stream>>>(buf, g1_w, g1_b, buf);
    agg_pool_atomic<<<NNODES / 4, 256, 0, stream>>>(buf, offs, csr, dinv,
                                                    bvec, cntinv, u);

    // ---- combine ----
    final_combine<<<NB / 256, 256, 0, stream>>>(epart, u, pre, out);
}

// Round 10
// 556.082 us; speedup vs baseline: 1.3346x; 1.3346x over previous
//
#include <hip/hip_runtime.h>

#define NNODES 262144
#define NEDGES 1048576
#define NB     4096

// ---------------------------------------------------------------------------
// Embedding GEMM fused with v1-dot:
// epart[m, by] = sum_{j in block-y cols} relu(smiles[m]@W1[:,j] + b1[j]) * v1[j]
// ---------------------------------------------------------------------------
__global__ __launch_bounds__(256) void emb_dot(
    const float* __restrict__ A, const float* __restrict__ B,
    const float* __restrict__ bias, const float* __restrict__ v1,
    float* __restrict__ epart)
{
    __shared__ float As[16][64];
    __shared__ float Bs[16][64];
    __shared__ float red[64][16];
    const int tid = threadIdx.x;
    const int tx = tid & 15, ty = tid >> 4;
    const int m0 = blockIdx.x * 64;
    const int n0 = blockIdx.y * 64;

    float acc[4][4] = {};
    const int ar = tid >> 2, aseg = tid & 3;
    const int bk = tid >> 4, bseg = tid & 15;
    const float* Aptr = A + (size_t)(m0 + ar) * 768 + aseg * 4;
    const float* Bptr = B + (size_t)bk * 1024 + n0 + bseg * 4;

    for (int k0 = 0; k0 < 768; k0 += 16) {
        float4 av = *(const float4*)(Aptr + k0);
        float4 bv = *(const float4*)(Bptr + (size_t)k0 * 1024);
        __syncthreads();
        As[aseg * 4 + 0][ar] = av.x;
        As[aseg * 4 + 1][ar] = av.y;
        As[aseg * 4 + 2][ar] = av.z;
        As[aseg * 4 + 3][ar] = av.w;
        *(float4*)&Bs[bk][bseg * 4] = bv;
        __syncthreads();
#pragma unroll
        for (int k = 0; k < 16; ++k) {
            float4 a4 = *(const float4*)&As[k][ty * 4];
            float4 b4 = *(const float4*)&Bs[k][tx * 4];
            float aa[4] = {a4.x, a4.y, a4.z, a4.w};
            float bb[4] = {b4.x, b4.y, b4.z, b4.w};
#pragma unroll
            for (int i = 0; i < 4; ++i)
#pragma unroll
                for (int j = 0; j < 4; ++j)
                    acc[i][j] += aa[i] * bb[j];
        }
    }

    float4 bb4 = *(const float4*)&bias[n0 + tx * 4];
    float4 vv4 = *(const float4*)&v1[n0 + tx * 4];
#pragma unroll
    for (int i = 0; i < 4; ++i) {
        float p = fmaxf(acc[i][0] + bb4.x, 0.f) * vv4.x
                + fmaxf(acc[i][1] + bb4.y, 0.f) * vv4.y
                + fmaxf(acc[i][2] + bb4.z, 0.f) * vv4.z
                + fmaxf(acc[i][3] + bb4.w, 0.f) * vv4.w;
        red[ty * 4 + i][tx] = p;
    }
    __syncthreads();
    if (tid < 64) {
        float s = 0.f;
#pragma unroll
        for (int c = 0; c < 16; ++c) s += red[tid][c];
        epart[(size_t)(m0 + tid) * 16 + blockIdx.y] = s;
    }
}

// ---------------------------------------------------------------------------
// GEMM fused with v2-dot and dinv pre-scale (replaces gemm_ip + 64MB h1):
// td[i] = dinv[i] * sum_j relu((A@g1_w)[i,j] + g1_b[j]) * v2[j]
// A: buf [N,64] (aggregated X). Writes only td[N] (1 MB).
// ---------------------------------------------------------------------------
__global__ __launch_bounds__(256) void gemm_dot(
    const float* __restrict__ A, const float* __restrict__ B,
    const float* __restrict__ bias, const float* __restrict__ v2,
    const float* __restrict__ dinv, float* __restrict__ td)
{
    __shared__ float As[16][64];
    __shared__ float Bs[16][64];
    __shared__ float red[64][16];
    const int tid = threadIdx.x;
    const int tx = tid & 15, ty = tid >> 4;
    const int m0 = blockIdx.x * 64;

    float acc[4][4] = {};
    const int ar = tid >> 2, aseg = tid & 3;
    const int bk = tid >> 4, bseg = tid & 15;
    const float* Aptr = A + (size_t)(m0 + ar) * 64 + aseg * 4;
    const float* Bptr = B + (size_t)bk * 64 + bseg * 4;

    for (int k0 = 0; k0 < 64; k0 += 16) {
        float4 av = *(const float4*)(Aptr + k0);
        float4 bv = *(const float4*)(Bptr + (size_t)k0 * 64);
        __syncthreads();
        As[aseg * 4 + 0][ar] = av.x;
        As[aseg * 4 + 1][ar] = av.y;
        As[aseg * 4 + 2][ar] = av.z;
        As[aseg * 4 + 3][ar] = av.w;
        *(float4*)&Bs[bk][bseg * 4] = bv;
        __syncthreads();
#pragma unroll
        for (int k = 0; k < 16; ++k) {
            float4 a4 = *(const float4*)&As[k][ty * 4];
            float4 b4 = *(const float4*)&Bs[k][tx * 4];
            float aa[4] = {a4.x, a4.y, a4.z, a4.w};
            float bb[4] = {b4.x, b4.y, b4.z, b4.w};
#pragma unroll
            for (int i = 0; i < 4; ++i)
#pragma unroll
                for (int j = 0; j < 4; ++j)
                    acc[i][j] += aa[i] * bb[j];
        }
    }

    float4 b4 = *(const float4*)&bias[tx * 4];
    float4 v4 = *(const float4*)&v2[tx * 4];
#pragma unroll
    for (int i = 0; i < 4; ++i) {
        float p = fmaxf(acc[i][0] + b4.x, 0.f) * v4.x
                + fmaxf(acc[i][1] + b4.y, 0.f) * v4.y
                + fmaxf(acc[i][2] + b4.z, 0.f) * v4.z
                + fmaxf(acc[i][3] + b4.w, 0.f) * v4.w;
        red[ty * 4 + i][tx] = p;
    }
    __syncthreads();
    if (tid < 64) {
        float s = 0.f;
#pragma unroll
        for (int c = 0; c < 16; ++c) s += red[tid][c];
        const int row = m0 + tid;
        td[row] = s * dinv[row];
    }
}

// ---------------------------------------------------------------------------
// CSR build
// ---------------------------------------------------------------------------
__global__ void count_deg(const int* __restrict__ dst, int* __restrict__ deg)
{
    int i = blockIdx.x * 256 + threadIdx.x;
    if (i < NEDGES) atomicAdd(&deg[dst[i]], 1);
}

__global__ void make_dinv(const int* __restrict__ deg, float* __restrict__ dinv)
{
    int i = blockIdx.x * 256 + threadIdx.x;
    if (i < NNODES) dinv[i] = rsqrtf((float)(deg[i] + 1));   // +1 self loop
}

__global__ __launch_bounds__(1024) void scan_block(
    const int* __restrict__ in, int* __restrict__ out, int* __restrict__ bsums)
{
    __shared__ int tmp[1024];
    const int tid = threadIdx.x;
    const int gid = blockIdx.x * 1024 + tid;
    int v = in[gid];
    tmp[tid] = v;
    __syncthreads();
    for (int off = 1; off < 1024; off <<= 1) {
        int t = (tid >= off) ? tmp[tid - off] : 0;
        __syncthreads();
        tmp[tid] += t;
        __syncthreads();
    }
    out[gid] = tmp[tid] - v;                 // exclusive
    if (tid == 1023) bsums[blockIdx.x] = tmp[tid];
}

__global__ __launch_bounds__(256) void scan_top(int* __restrict__ bsums)
{
    __shared__ int tmp[256];
    const int tid = threadIdx.x;
    int v = bsums[tid];
    tmp[tid] = v;
    __syncthreads();
    for (int off = 1; off < 256; off <<= 1) {
        int t = (tid >= off) ? tmp[tid - off] : 0;
        __syncthreads();
        tmp[tid] += t;
        __syncthreads();
    }
    bsums[tid] = tmp[tid] - v;
}

__global__ void scan_add(int* __restrict__ out, const int* __restrict__ bsums)
{
    int gid = blockIdx.x * 256 + threadIdx.x;
    out[gid] += bsums[gid >> 10];
}

__global__ void scatter_edges(const int* __restrict__ src, const int* __restrict__ dst,
                              int* __restrict__ cur, int* __restrict__ csr)
{
    int i = blockIdx.x * 256 + threadIdx.x;
    if (i < NEDGES) {
        int d = dst[i];
        int pos = atomicAdd(&cur[d], 1);
        csr[pos] = src[i];
    }
}

// ---------------------------------------------------------------------------
// 64-wide aggregation of node_x (layer 1): wave per node, lane = feature.
// Edge loop unrolled x4 -> 4 independent 256B gathers in flight per wave.
// out[i] = sum_s x[s]*dinv[s]*dinv[i] + x[i]*dinv[i]^2
// ---------------------------------------------------------------------------
__global__ __launch_bounds__(256) void agg_plain(
    const float* __restrict__ h, const int* __restrict__ offs,
    const int* __restrict__ csr, const float* __restrict__ dinv,
    float* __restrict__ out)
{
    const int wid = (blockIdx.x * 256 + threadIdx.x) >> 6;
    const int lane = threadIdx.x & 63;
    if (wid >= NNODES) return;
    const float di = dinv[wid];
    float acc = h[(size_t)wid * 64 + lane] * di * di;
    int e = offs[wid];
    const int e1 = (wid + 1 < NNODES) ? offs[wid + 1] : NEDGES;
    for (; e + 4 <= e1; e += 4) {
        const int s0 = csr[e + 0], s1 = csr[e + 1];
        const int s2 = csr[e + 2], s3 = csr[e + 3];
        const float w0 = dinv[s0] * di, w1 = dinv[s1] * di;
        const float w2 = dinv[s2] * di, w3 = dinv[s3] * di;
        const float h0 = h[(size_t)s0 * 64 + lane];
        const float h1 = h[(size_t)s1 * 64 + lane];
        const float h2 = h[(size_t)s2 * 64 + lane];
        const float h3 = h[(size_t)s3 * 64 + lane];
        acc += h0 * w0 + h1 * w1 + h2 * w2 + h3 * w3;
    }
    for (; e < e1; ++e) {
        const int s = csr[e];
        acc += h[(size_t)s * 64 + lane] * (dinv[s] * di);
    }
    out[(size_t)wid * 64 + lane] = acc;
}

// ---------------------------------------------------------------------------
// Scalar aggregation (layer 2 folded to width 1): thread per node.
// z[i] = dinv[i] * (td[i] + sum_{s in N(i)} td[s]); td is 1 MB, L2-resident.
// ---------------------------------------------------------------------------
__global__ void agg_scalar(
    const float* __restrict__ td, const int* __restrict__ offs,
    const int* __restrict__ csr, const float* __restrict__ dinv,
    float* __restrict__ z)
{
    int i = blockIdx.x * 256 + threadIdx.x;
    if (i >= NNODES) return;
    float s = td[i];
    const int e0 = offs[i];
    const int e1 = (i + 1 < NNODES) ? offs[i + 1] : NEDGES;
    for (int e = e0; e < e1; ++e) s += td[csr[e]];
    z[i] = s * dinv[i];
}

// Segment mean of z per graph (sorted batch_vec -> contiguous, coalesced).
__global__ __launch_bounds__(256) void pool_dot(
    const float* __restrict__ z, const int* __restrict__ start,
    const float* __restrict__ cntinv, float* __restrict__ gpart)
{
    const int g = (blockIdx.x * 256 + threadIdx.x) >> 6;
    const int lane = threadIdx.x & 63;
    if (g >= NB) return;
    const int s0 = start[g], s1 = start[g + 1];
    float a = 0.f;
    for (int i = s0 + lane; i < s1; i += 64) a += z[i];
#pragma unroll
    for (int off = 32; off; off >>= 1) a += __shfl_down(a, off, 64);
    if (lane == 0) gpart[g] = a * cntinv[g];
}

// ---------------------------------------------------------------------------
// Graph segment boundaries (batch_vec is sorted) + inverse counts
// ---------------------------------------------------------------------------
__global__ void graph_starts(const int* __restrict__ bv, int* __restrict__ start)
{
    int g = blockIdx.x * 256 + threadIdx.x;
    if (g > NB) return;
    if (g == NB) { start[g] = NNODES; return; }
    int lo = 0, hi = NNODES;
    while (lo < hi) {
        int mid = (lo + hi) >> 1;
        if (bv[mid] < g) lo = mid + 1; else hi = mid;
    }
    start[g] = lo;
}

__global__ void make_cntinv(const int* __restrict__ start, float* __restrict__ cntinv)
{
    int g = blockIdx.x * 256 + threadIdx.x;
    if (g < NB) cntinv[g] = 1.0f / fmaxf((float)(start[g + 1] - start[g]), 1.0f);
}

// ---------------------------------------------------------------------------
// Precompute folded weight vectors (tail is affine).
// pre layout (floats): [0:128) p1, [128:256) p2, [256:384) wfinal,
//                      [384:512) q1, [512:576) v2, [576:1600) v1, [1600] c0
// ---------------------------------------------------------------------------
__global__ __launch_bounds__(256) void precompute(
    const float* __restrict__ emb_w2, const float* __restrict__ emb_b2,
    const float* __restrict__ g2_w, const float* __restrict__ g2_b,
    const float* __restrict__ gfc_w, const float* __restrict__ gfc_b,
    const float* __restrict__ v_b,
    const float* __restrict__ o_w, const float* __restrict__ o_b,
    const float* __restrict__ f1_w, const float* __restrict__ f1_b,
    const float* __restrict__ ff_w, const float* __restrict__ ff_b,
    const float* __restrict__ v_w, float* __restrict__ pre)
{
    const int tid = threadIdx.x;
    float* p1 = pre;           // [128]
    float* p2 = pre + 128;     // [128]
    float* wf = pre + 256;     // [128]
    float* q1 = pre + 384;     // [128]
    float* v2 = pre + 512;     // [64]
    float* v1 = pre + 576;     // [1024]

    if (tid < 128) {                         // p1 = f1_w @ ff_w
        float s = 0.f;
        for (int k = 0; k < 64; ++k) s += f1_w[tid * 64 + k] * ff_w[k];
        p1[tid] = s;
    }
    __syncthreads();
    if (tid < 128) {                         // p2 = o_w @ p1
        float s = 0.f;
        for (int k = 0; k < 128; ++k) s += o_w[tid * 128 + k] * p1[k];
        p2[tid] = s;
    }
    __syncthreads();
    if (tid < 128) {                         // wfinal = v_w @ p2
        float s = 0.f;
        for (int k = 0; k < 128; ++k) s += v_w[tid * 128 + k] * p2[k];
        wf[tid] = s;
    }
    __syncthreads();
    if (tid < 128) {                         // q1 = gfc_w @ wf2
        float s = 0.f;
        for (int k = 0; k < 64; ++k) s += gfc_w[tid * 64 + k] * wf[64 + k];
        q1[tid] = s;
    }
    __syncthreads();
    if (tid < 64) {                          // v2 = g2_w @ q1
        float s = 0.f;
        for (int k = 0; k < 128; ++k) s += g2_w[tid * 128 + k] * q1[k];
        v2[tid] = s;
    }
    for (int r = 0; r < 4; ++r) {            // v1 = emb_w2 @ wf1
        int j = tid + 256 * r;
        float s = 0.f;
        for (int k = 0; k < 64; ++k) s += emb_w2[j * 64 + k] * wf[k];
        v1[j] = s;
    }
    if (tid == 0) {                          // c0 (all bias-chain dots)
        float c = ff_b[0];
        for (int k = 0; k < 64; ++k)  c += f1_b[k] * ff_w[k];
        for (int i = 0; i < 128; ++i) c += o_b[i] * p1[i] + v_b[i] * p2[i];
        for (int k = 0; k < 64; ++k)  c += emb_b2[k] * wf[k];
        for (int i = 0; i < 128; ++i) c += g2_b[i] * q1[i];
        for (int k = 0; k < 64; ++k)  c += gfc_b[k] * wf[64 + k];
        pre[1600] = c;
    }
}

// out[b] = sum_c epart[b,c] + gpart[b] + c0
__global__ void final_combine(
    const float* __restrict__ epart, const float* __restrict__ gpart,
    const float* __restrict__ pre, float* __restrict__ out)
{
    int b = blockIdx.x * 256 + threadIdx.x;
    if (b >= NB) return;
    float s = pre[1600] + gpart[b];
    const float* ep = &epart[(size_t)b * 16];
#pragma unroll
    for (int c = 0; c < 16; ++c) s += ep[c];
    out[b] = s;
}

// ---------------------------------------------------------------------------
extern "C" void kernel_launch(void* const* d_in, const int* in_sizes, int n_in,
                              void* d_out, int out_size, void* d_ws, size_t ws_size,
                              hipStream_t stream)
{
    const float* smiles = (const float*)d_in[0];    // [4096,1,768]
    const float* node_x = (const float*)d_in[1];    // [262144,64]
    const int*   esrc   = (const int*)d_in[2];
    const int*   edst   = (const int*)d_in[3];
    const int*   bvec   = (const int*)d_in[4];      // sorted
    const float* emb_w1 = (const float*)d_in[5];    // [768,1024]
    const float* emb_b1 = (const float*)d_in[6];
    const float* emb_w2 = (const float*)d_in[7];    // [1024,64]
    const float* emb_b2 = (const float*)d_in[8];
    const float* g1_w   = (const float*)d_in[9];    // [64,64]
    const float* g1_b   = (const float*)d_in[10];
    const float* g2_w   = (const float*)d_in[11];   // [64,128]
    const float* g2_b   = (const float*)d_in[12];
    const float* gfc_w  = (const float*)d_in[13];   // [128,64]
    const float* gfc_b  = (const float*)d_in[14];
    // q_w/q_b/k_w/k_b (15..18) dead: S=1 collapses top-k softmax to identity
    const float* v_w    = (const float*)d_in[19];   // [128,128]
    const float* v_b    = (const float*)d_in[20];
    const float* o_w    = (const float*)d_in[21];   // [128,128]
    const float* o_b    = (const float*)d_in[22];
    const float* f1_w   = (const float*)d_in[23];   // [128,64]
    const float* f1_b   = (const float*)d_in[24];
    const float* ff_w   = (const float*)d_in[25];   // [64,1]
    const float* ff_b   = (const float*)d_in[26];   // [1]
    float* out = (float*)d_out;

    // workspace carve-up (total ~74 MB)
    char* ws = (char*)d_ws;
    size_t off = 0;
    auto alloc = [&](size_t b) -> void* {
        void* p = ws + off;
        off += (b + 255) & ~(size_t)255;
        return p;
    };
    float* buf    = (float*)alloc((size_t)NNODES * 64 * 4);   // 64 MB
    int*   deg    = (int*)alloc((size_t)NNODES * 4);
    int*   offs   = (int*)alloc((size_t)NNODES * 4);
    int*   cur    = (int*)alloc((size_t)NNODES * 4);
    float* dinv   = (float*)alloc((size_t)NNODES * 4);
    int*   csr    = (int*)alloc((size_t)NEDGES * 4);
    int*   startg = (int*)alloc((size_t)(NB + 1) * 4);
    int*   bsums  = (int*)alloc(256 * 4);
    float* cntinv = (float*)alloc((size_t)NB * 4);
    float* epart  = (float*)alloc((size_t)NB * 16 * 4);
    float* td     = (float*)alloc((size_t)NNODES * 4);
    float* zbuf   = (float*)alloc((size_t)NNODES * 4);
    float* gpart  = (float*)alloc((size_t)NB * 4);
    float* pre    = (float*)alloc(2048 * 4);

    // ---- CSR build (int atomics only) ----
    hipMemsetAsync(deg, 0, (size_t)NNODES * 4, stream);
    count_deg<<<NEDGES / 256, 256, 0, stream>>>(edst, deg);
    make_dinv<<<NNODES / 256, 256, 0, stream>>>(deg, dinv);
    scan_block<<<NNODES / 1024, 1024, 0, stream>>>(deg, offs, bsums);
    scan_top<<<1, 256, 0, stream>>>(bsums);
    scan_add<<<NNODES / 256, 256, 0, stream>>>(offs, bsums);
    hipMemcpyAsync(cur, offs, (size_t)NNODES * 4, hipMemcpyDeviceToDevice, stream);
    scatter_edges<<<NEDGES / 256, 256, 0, stream>>>(esrc, edst, cur, csr);
    graph_starts<<<(NB + 256) / 256, 256, 0, stream>>>(bvec, startg);
    make_cntinv<<<NB / 256, 256, 0, stream>>>(startg, cntinv);

    // ---- folded tail weights ----
    precompute<<<1, 256, 0, stream>>>(emb_w2, emb_b2, g2_w, g2_b, gfc_w, gfc_b,
                                      v_b, o_w, o_b, f1_w, f1_b, ff_w, ff_b,
                                      v_w, pre);

    // ---- embedding branch: relu(smiles@W1+b1) . v1 -> epart[B,16] ----
    emb_dot<<<dim3(NB / 64, 16), 256, 0, stream>>>(smiles, emb_w1, emb_b1,
                                                   pre + 576, epart);

    // ---- GCN branch (aggregation #2 folded to scalar width) ----
    agg_plain<<<NNODES / 4, 256, 0, stream>>>(node_x, offs, csr, dinv, buf);
    gemm_dot<<<NNODES / 64, 256, 0, stream>>>(buf, g1_w, g1_b, pre + 512,
                                              dinv, td);
    agg_scalar<<<NNODES / 256, 256, 0, stream>>>(td, offs, csr, dinv, zbuf);
    pool_dot<<<NB / 4, 256, 0, stream>>>(zbuf, startg, cntinv, gpart);

    // ---- combine ----
    final_combine<<<NB / 256, 256, 0, stream>>>(epart, gpart, pre, out);
}

// Round 12
// 471.634 us; speedup vs baseline: 1.5736x; 1.1791x over previous
//
#include <hip/hip_runtime.h>

#define NNODES 262144
#define NEDGES 1048576
#define NB     4096

typedef __attribute__((ext_vector_type(8))) short short8v;   // 8 bf16 (4 VGPRs)
typedef __attribute__((ext_vector_type(4))) float f32x4;     // MFMA acc

__device__ __forceinline__ unsigned short f2bf(float f) {    // RNE float->bf16
    unsigned int u = __float_as_uint(f);
    u += 0x7FFFu + ((u >> 16) & 1u);
    return (unsigned short)(u >> 16);
}

// ---------------------------------------------------------------------------
// Embedding branch via bf16 MFMA, fused with v1-dot:
// epart[m, by] = sum_j relu(smiles[m]@W1[:,j]+b1[j]) * v1[j], j in by's 64 cols
// Block: 64 rows x 64 cols, 4 waves; wave w owns rows w*16..+16.
// Frag maps (m89-verified): A row=lane&15, k=8*(lane>>4)+i; B col=lane&15 same k;
// D row=4*(lane>>4)+i, col=lane&15.
// ---------------------------------------------------------------------------
__global__ __launch_bounds__(256) void emb_mfma(
    const float* __restrict__ A, const float* __restrict__ B,
    const float* __restrict__ bias, const float* __restrict__ v1,
    float* __restrict__ epart)
{
    __shared__ __align__(16) unsigned short Asb[64][80];  // [row][k] bf16, pad->160B stride
    __shared__ __align__(16) unsigned short Btb[64][80];  // [col][k] bf16 (W transposed)
    __shared__ float red[64][16];
    const int tid = threadIdx.x;
    const int w = tid >> 6, lane = tid & 63;
    const int m0 = blockIdx.x * 64, n0 = blockIdx.y * 64;

    f32x4 acc[4] = {{0.f,0.f,0.f,0.f},{0.f,0.f,0.f,0.f},
                    {0.f,0.f,0.f,0.f},{0.f,0.f,0.f,0.f}};

    const int ar = tid >> 2, ak4 = (tid & 3) * 4;  // A stage: row, k-base
    const int bk = tid >> 2, bc4 = (tid & 3) * 4;  // B stage: k-row, col-base

    for (int k0 = 0; k0 < 768; k0 += 64) {
        __syncthreads();   // prior iteration's frag reads done
        {
            const float* src = A + (size_t)(m0 + ar) * 768 + k0 + ak4;
#pragma unroll
            for (int rep = 0; rep < 4; ++rep) {
                float4 v = *(const float4*)(src + rep * 16);
                unsigned long long pk =
                      (unsigned long long)f2bf(v.x)
                    | ((unsigned long long)f2bf(v.y) << 16)
                    | ((unsigned long long)f2bf(v.z) << 32)
                    | ((unsigned long long)f2bf(v.w) << 48);
                *(unsigned long long*)&Asb[ar][ak4 + rep * 16] = pk;
            }
        }
        {
            const float* src = B + (size_t)(k0 + bk) * 1024 + n0 + bc4;
#pragma unroll
            for (int rep = 0; rep < 4; ++rep) {
                float4 v = *(const float4*)(src + rep * 16);
                Btb[bc4 + rep * 16 + 0][bk] = f2bf(v.x);
                Btb[bc4 + rep * 16 + 1][bk] = f2bf(v.y);
                Btb[bc4 + rep * 16 + 2][bk] = f2bf(v.z);
                Btb[bc4 + rep * 16 + 3][bk] = f2bf(v.w);
            }
        }
        __syncthreads();
#pragma unroll
        for (int ks = 0; ks < 2; ++ks) {
            short8v af = *(const short8v*)&Asb[w * 16 + (lane & 15)][ks * 32 + 8 * (lane >> 4)];
#pragma unroll
            for (int ct = 0; ct < 4; ++ct) {
                short8v bf = *(const short8v*)&Btb[ct * 16 + (lane & 15)][ks * 32 + 8 * (lane >> 4)];
                acc[ct] = __builtin_amdgcn_mfma_f32_16x16x32_bf16(af, bf, acc[ct], 0, 0, 0);
            }
        }
    }

    float p[4] = {0.f, 0.f, 0.f, 0.f};
#pragma unroll
    for (int ct = 0; ct < 4; ++ct) {
        const int col = n0 + ct * 16 + (lane & 15);
        const float bcv = bias[col], vcv = v1[col];
#pragma unroll
        for (int i = 0; i < 4; ++i)
            p[i] += fmaxf(acc[ct][i] + bcv, 0.f) * vcv;
    }
#pragma unroll
    for (int i = 0; i < 4; ++i)
        red[w * 16 + 4 * (lane >> 4) + i][lane & 15] = p[i];
    __syncthreads();
    if (tid < 64) {
        float s = 0.f;
#pragma unroll
        for (int c = 0; c < 16; ++c) s += red[tid][c];
        epart[(size_t)(m0 + tid) * 16 + blockIdx.y] = s;
    }
}

// ---------------------------------------------------------------------------
// GEMM fused with v2-dot and dinv pre-scale:
// td[i] = dinv[i] * sum_j relu((A@g1_w)[i,j] + g1_b[j]) * v2[j]
// ---------------------------------------------------------------------------
__global__ __launch_bounds__(256) void gemm_dot(
    const float* __restrict__ A, const float* __restrict__ B,
    const float* __restrict__ bias, const float* __restrict__ v2,
    const float* __restrict__ dinv, float* __restrict__ td)
{
    __shared__ float As[16][64];
    __shared__ float Bs[16][64];
    __shared__ float red[64][16];
    const int tid = threadIdx.x;
    const int tx = tid & 15, ty = tid >> 4;
    const int m0 = blockIdx.x * 64;

    float acc[4][4] = {};
    const int ar = tid >> 2, aseg = tid & 3;
    const int bk = tid >> 4, bseg = tid & 15;
    const float* Aptr = A + (size_t)(m0 + ar) * 64 + aseg * 4;
    const float* Bptr = B + (size_t)bk * 64 + bseg * 4;

    for (int k0 = 0; k0 < 64; k0 += 16) {
        float4 av = *(const float4*)(Aptr + k0);
        float4 bv = *(const float4*)(Bptr + (size_t)k0 * 64);
        __syncthreads();
        As[aseg * 4 + 0][ar] = av.x;
        As[aseg * 4 + 1][ar] = av.y;
        As[aseg * 4 + 2][ar] = av.z;
        As[aseg * 4 + 3][ar] = av.w;
        *(float4*)&Bs[bk][bseg * 4] = bv;
        __syncthreads();
#pragma unroll
        for (int k = 0; k < 16; ++k) {
            float4 a4 = *(const float4*)&As[k][ty * 4];
            float4 b4 = *(const float4*)&Bs[k][tx * 4];
            float aa[4] = {a4.x, a4.y, a4.z, a4.w};
            float bb[4] = {b4.x, b4.y, b4.z, b4.w};
#pragma unroll
            for (int i = 0; i < 4; ++i)
#pragma unroll
                for (int j = 0; j < 4; ++j)
                    acc[i][j] += aa[i] * bb[j];
        }
    }

    float4 b4 = *(const float4*)&bias[tx * 4];
    float4 v4 = *(const float4*)&v2[tx * 4];
#pragma unroll
    for (int i = 0; i < 4; ++i) {
        float p = fmaxf(acc[i][0] + b4.x, 0.f) * v4.x
                + fmaxf(acc[i][1] + b4.y, 0.f) * v4.y
                + fmaxf(acc[i][2] + b4.z, 0.f) * v4.z
                + fmaxf(acc[i][3] + b4.w, 0.f) * v4.w;
        red[ty * 4 + i][tx] = p;
    }
    __syncthreads();
    if (tid < 64) {
        float s = 0.f;
#pragma unroll
        for (int c = 0; c < 16; ++c) s += red[tid][c];
        const int row = m0 + tid;
        td[row] = s * dinv[row];
    }
}

// ---------------------------------------------------------------------------
// CSR build
// ---------------------------------------------------------------------------
__global__ void count_deg(const int* __restrict__ dst, int* __restrict__ deg)
{
    int i = blockIdx.x * 256 + threadIdx.x;
    if (i < NEDGES) atomicAdd(&deg[dst[i]], 1);
}

__global__ void make_dinv(const int* __restrict__ deg, float* __restrict__ dinv)
{
    int i = blockIdx.x * 256 + threadIdx.x;
    if (i < NNODES) dinv[i] = rsqrtf((float)(deg[i] + 1));   // +1 self loop
}

__global__ __launch_bounds__(1024) void scan_block(
    const int* __restrict__ in, int* __restrict__ out, int* __restrict__ bsums)
{
    __shared__ int tmp[1024];
    const int tid = threadIdx.x;
    const int gid = blockIdx.x * 1024 + tid;
    int v = in[gid];
    tmp[tid] = v;
    __syncthreads();
    for (int off = 1; off < 1024; off <<= 1) {
        int t = (tid >= off) ? tmp[tid - off] : 0;
        __syncthreads();
        tmp[tid] += t;
        __syncthreads();
    }
    out[gid] = tmp[tid] - v;                 // exclusive
    if (tid == 1023) bsums[blockIdx.x] = tmp[tid];
}

__global__ __launch_bounds__(256) void scan_top(int* __restrict__ bsums)
{
    __shared__ int tmp[256];
    const int tid = threadIdx.x;
    int v = bsums[tid];
    tmp[tid] = v;
    __syncthreads();
    for (int off = 1; off < 256; off <<= 1) {
        int t = (tid >= off) ? tmp[tid - off] : 0;
        __syncthreads();
        tmp[tid] += t;
        __syncthreads();
    }
    bsums[tid] = tmp[tid] - v;
}

__global__ void scan_add(int* __restrict__ out, const int* __restrict__ bsums)
{
    int gid = blockIdx.x * 256 + threadIdx.x;
    out[gid] += bsums[gid >> 10];
}

__global__ void scatter_edges(const int* __restrict__ src, const int* __restrict__ dst,
                              int* __restrict__ cur, int* __restrict__ csr)
{
    int i = blockIdx.x * 256 + threadIdx.x;
    if (i < NEDGES) {
        int d = dst[i];
        int pos = atomicAdd(&cur[d], 1);
        csr[pos] = src[i];
    }
}

// ---------------------------------------------------------------------------
// Layer-1 aggregation: wave per FOUR consecutive nodes (their CSR ranges are
// contiguous), lane = feature. 8-deep edge unroll -> 8 random 256B gathers in
// flight per wave (2x the old 4). Node selection per edge is wave-uniform.
// ---------------------------------------------------------------------------
__global__ __launch_bounds__(256) void agg_plain4(
    const float* __restrict__ h, const int* __restrict__ offs,
    const int* __restrict__ csr, const float* __restrict__ dinv,
    float* __restrict__ out)
{
    const int q = (blockIdx.x * 256 + threadIdx.x) >> 6;
    const int lane = threadIdx.x & 63;
    const int n0 = q * 4;
    if (n0 >= NNODES) return;

    const int o0 = offs[n0];
    const int o1 = offs[n0 + 1];
    const int o2 = offs[n0 + 2];
    const int o3 = offs[n0 + 3];
    const int o4 = (n0 + 4 < NNODES) ? offs[n0 + 4] : NEDGES;

    const float d0 = dinv[n0], d1 = dinv[n0 + 1];
    const float d2 = dinv[n0 + 2], d3 = dinv[n0 + 3];

    float a0 = h[(size_t)(n0 + 0) * 64 + lane] * d0 * d0;
    float a1 = h[(size_t)(n0 + 1) * 64 + lane] * d1 * d1;
    float a2 = h[(size_t)(n0 + 2) * 64 + lane] * d2 * d2;
    float a3 = h[(size_t)(n0 + 3) * 64 + lane] * d3 * d3;

    int e = o0;
    for (; e + 8 <= o4; e += 8) {
        int s[8];
#pragma unroll
        for (int u = 0; u < 8; ++u) s[u] = csr[e + u];
        float wv[8];
#pragma unroll
        for (int u = 0; u < 8; ++u) wv[u] = dinv[s[u]];
        float hv[8];
#pragma unroll
        for (int u = 0; u < 8; ++u) hv[u] = h[(size_t)s[u] * 64 + lane];
#pragma unroll
        for (int u = 0; u < 8; ++u) {
            const int ei = e + u;               // wave-uniform -> scalar branch
            const float c = hv[u] * wv[u];
            if      (ei < o1) a0 += c * d0;
            else if (ei < o2) a1 += c * d1;
            else if (ei < o3) a2 += c * d2;
            else              a3 += c * d3;
        }
    }
    for (; e < o4; ++e) {
        const int s = csr[e];
        const float c = h[(size_t)s * 64 + lane] * dinv[s];
        if      (e < o1) a0 += c * d0;
        else if (e < o2) a1 += c * d1;
        else if (e < o3) a2 += c * d2;
        else             a3 += c * d3;
    }

    out[(size_t)(n0 + 0) * 64 + lane] = a0;
    out[(size_t)(n0 + 1) * 64 + lane] = a1;
    out[(size_t)(n0 + 2) * 64 + lane] = a2;
    out[(size_t)(n0 + 3) * 64 + lane] = a3;
}

// ---------------------------------------------------------------------------
// Scalar aggregation (layer 2 folded to width 1): thread per node.
// ---------------------------------------------------------------------------
__global__ void agg_scalar(
    const float* __restrict__ td, const int* __restrict__ offs,
    const int* __restrict__ csr, const float* __restrict__ dinv,
    float* __restrict__ z)
{
    int i = blockIdx.x * 256 + threadIdx.x;
    if (i >= NNODES) return;
    float s = td[i];
    const int e0 = offs[i];
    const int e1 = (i + 1 < NNODES) ? offs[i + 1] : NEDGES;
    for (int e = e0; e < e1; ++e) s += td[csr[e]];
    z[i] = s * dinv[i];
}

// Segment mean of z per graph (sorted batch_vec -> contiguous, coalesced).
__global__ __launch_bounds__(256) void pool_dot(
    const float* __restrict__ z, const int* __restrict__ start,
    const float* __restrict__ cntinv, float* __restrict__ gpart)
{
    const int g = (blockIdx.x * 256 + threadIdx.x) >> 6;
    const int lane = threadIdx.x & 63;
    if (g >= NB) return;
    const int s0 = start[g], s1 = start[g + 1];
    float a = 0.f;
    for (int i = s0 + lane; i < s1; i += 64) a += z[i];
#pragma unroll
    for (int off = 32; off; off >>= 1) a += __shfl_down(a, off, 64);
    if (lane == 0) gpart[g] = a * cntinv[g];
}

// ---------------------------------------------------------------------------
// Graph segment boundaries + inverse counts
// ---------------------------------------------------------------------------
__global__ void graph_starts(const int* __restrict__ bv, int* __restrict__ start)
{
    int g = blockIdx.x * 256 + threadIdx.x;
    if (g > NB) return;
    if (g == NB) { start[g] = NNODES; return; }
    int lo = 0, hi = NNODES;
    while (lo < hi) {
        int mid = (lo + hi) >> 1;
        if (bv[mid] < g) lo = mid + 1; else hi = mid;
    }
    start[g] = lo;
}

__global__ void make_cntinv(const int* __restrict__ start, float* __restrict__ cntinv)
{
    int g = blockIdx.x * 256 + threadIdx.x;
    if (g < NB) cntinv[g] = 1.0f / fmaxf((float)(start[g + 1] - start[g]), 1.0f);
}

// ---------------------------------------------------------------------------
// Precompute folded weight vectors (tail is affine).
// pre layout (floats): [0:128) p1, [128:256) p2, [256:384) wfinal,
//                      [384:512) q1, [512:576) v2, [576:1600) v1, [1600] c0
// ---------------------------------------------------------------------------
__global__ __launch_bounds__(256) void precompute(
    const float* __restrict__ emb_w2, const float* __restrict__ emb_b2,
    const float* __restrict__ g2_w, const float* __restrict__ g2_b,
    const float* __restrict__ gfc_w, const float* __restrict__ gfc_b,
    const float* __restrict__ v_b,
    const float* __restrict__ o_w, const float* __restrict__ o_b,
    const float* __restrict__ f1_w, const float* __restrict__ f1_b,
    const float* __restrict__ ff_w, const float* __restrict__ ff_b,
    const float* __restrict__ v_w, float* __restrict__ pre)
{
    const int tid = threadIdx.x;
    float* p1 = pre;           // [128]
    float* p2 = pre + 128;     // [128]
    float* wf = pre + 256;     // [128]
    float* q1 = pre + 384;     // [128]
    float* v2 = pre + 512;     // [64]
    float* v1 = pre + 576;     // [1024]

    if (tid < 128) {                         // p1 = f1_w @ ff_w
        float s = 0.f;
        for (int k = 0; k < 64; ++k) s += f1_w[tid * 64 + k] * ff_w[k];
        p1[tid] = s;
    }
    __syncthreads();
    if (tid < 128) {                         // p2 = o_w @ p1
        float s = 0.f;
        for (int k = 0; k < 128; ++k) s += o_w[tid * 128 + k] * p1[k];
        p2[tid] = s;
    }
    __syncthreads();
    if (tid < 128) {                         // wfinal = v_w @ p2
        float s = 0.f;
        for (int k = 0; k < 128; ++k) s += v_w[tid * 128 + k] * p2[k];
        wf[tid] = s;
    }
    __syncthreads();
    if (tid < 128) {                         // q1 = gfc_w @ wf2
        float s = 0.f;
        for (int k = 0; k < 64; ++k) s += gfc_w[tid * 64 + k] * wf[64 + k];
        q1[tid] = s;
    }
    __syncthreads();
    if (tid < 64) {                          // v2 = g2_w @ q1
        float s = 0.f;
        for (int k = 0; k < 128; ++k) s += g2_w[tid * 128 + k] * q1[k];
        v2[tid] = s;
    }
    for (int r = 0; r < 4; ++r) {            // v1 = emb_w2 @ wf1
        int j = tid + 256 * r;
        float s = 0.f;
        for (int k = 0; k < 64; ++k) s += emb_w2[j * 64 + k] * wf[k];
        v1[j] = s;
    }
    if (tid == 0) {                          // c0 (all bias-chain dots)
        float c = ff_b[0];
        for (int k = 0; k < 64; ++k)  c += f1_b[k] * ff_w[k];
        for (int i = 0; i < 128; ++i) c += o_b[i] * p1[i] + v_b[i] * p2[i];
        for (int k = 0; k < 64; ++k)  c += emb_b2[k] * wf[k];
        for (int i = 0; i < 128; ++i) c += g2_b[i] * q1[i];
        for (int k = 0; k < 64; ++k)  c += gfc_b[k] * wf[64 + k];
        pre[1600] = c;
    }
}

// out[b] = sum_c epart[b,c] + gpart[b] + c0
__global__ void final_combine(
    const float* __restrict__ epart, const float* __restrict__ gpart,
    const float* __restrict__ pre, float* __restrict__ out)
{
    int b = blockIdx.x * 256 + threadIdx.x;
    if (b >= NB) return;
    float s = pre[1600] + gpart[b];
    const float* ep = &epart[(size_t)b * 16];
#pragma unroll
    for (int c = 0; c < 16; ++c) s += ep[c];
    out[b] = s;
}

// ---------------------------------------------------------------------------
extern "C" void kernel_launch(void* const* d_in, const int* in_sizes, int n_in,
                              void* d_out, int out_size, void* d_ws, size_t ws_size,
                              hipStream_t stream)
{
    const float* smiles = (const float*)d_in[0];    // [4096,1,768]
    const float* node_x = (const float*)d_in[1];    // [262144,64]
    const int*   esrc   = (const int*)d_in[2];
    const int*   edst   = (const int*)d_in[3];
    const int*   bvec   = (const int*)d_in[4];      // sorted
    const float* emb_w1 = (const float*)d_in[5];    // [768,1024]
    const float* emb_b1 = (const float*)d_in[6];
    const float* emb_w2 = (const float*)d_in[7];    // [1024,64]
    const float* emb_b2 = (const float*)d_in[8];
    const float* g1_w   = (const float*)d_in[9];    // [64,64]
    const float* g1_b   = (const float*)d_in[10];
    const float* g2_w   = (const float*)d_in[11];   // [64,128]
    const float* g2_b   = (const float*)d_in[12];
    const float* gfc_w  = (const float*)d_in[13];   // [128,64]
    const float* gfc_b  = (const float*)d_in[14];
    // q_w/q_b/k_w/k_b (15..18) dead: S=1 collapses top-k softmax to identity
    const float* v_w    = (const float*)d_in[19];   // [128,128]
    const float* v_b    = (const float*)d_in[20];
    const float* o_w    = (const float*)d_in[21];   // [128,128]
    const float* o_b    = (const float*)d_in[22];
    const float* f1_w   = (const float*)d_in[23];   // [128,64]
    const float* f1_b   = (const float*)d_in[24];
    const float* ff_w   = (const float*)d_in[25];   // [64,1]
    const float* ff_b   = (const float*)d_in[26];   // [1]
    float* out = (float*)d_out;

    // workspace carve-up (total ~74 MB)
    char* ws = (char*)d_ws;
    size_t off = 0;
    auto alloc = [&](size_t b) -> void* {
        void* p = ws + off;
        off += (b + 255) & ~(size_t)255;
        return p;
    };
    float* buf    = (float*)alloc((size_t)NNODES * 64 * 4);   // 64 MB
    int*   deg    = (int*)alloc((size_t)NNODES * 4);
    int*   offs   = (int*)alloc((size_t)NNODES * 4);
    int*   cur    = (int*)alloc((size_t)NNODES * 4);
    float* dinv   = (float*)alloc((size_t)NNODES * 4);
    int*   csr    = (int*)alloc((size_t)NEDGES * 4);
    int*   startg = (int*)alloc((size_t)(NB + 1) * 4);
    int*   bsums  = (int*)alloc(256 * 4);
    float* cntinv = (float*)alloc((size_t)NB * 4);
    float* epart  = (float*)alloc((size_t)NB * 16 * 4);
    float* td     = (float*)alloc((size_t)NNODES * 4);
    float* zbuf   = (float*)alloc((size_t)NNODES * 4);
    float* gpart  = (float*)alloc((size_t)NB * 4);
    float* pre    = (float*)alloc(2048 * 4);

    // ---- CSR build (int atomics only) ----
    hipMemsetAsync(deg, 0, (size_t)NNODES * 4, stream);
    count_deg<<<NEDGES / 256, 256, 0, stream>>>(edst, deg);
    make_dinv<<<NNODES / 256, 256, 0, stream>>>(deg, dinv);
    scan_block<<<NNODES / 1024, 1024, 0, stream>>>(deg, offs, bsums);
    scan_top<<<1, 256, 0, stream>>>(bsums);
    scan_add<<<NNODES / 256, 256, 0, stream>>>(offs, bsums);
    hipMemcpyAsync(cur, offs, (size_t)NNODES * 4, hipMemcpyDeviceToDevice, stream);
    scatter_edges<<<NEDGES / 256, 256, 0, stream>>>(esrc, edst, cur, csr);
    graph_starts<<<(NB + 256) / 256, 256, 0, stream>>>(bvec, startg);
    make_cntinv<<<NB / 256, 256, 0, stream>>>(startg, cntinv);

    // ---- folded tail weights ----
    precompute<<<1, 256, 0, stream>>>(emb_w2, emb_b2, g2_w, g2_b, gfc_w, gfc_b,
                                      v_b, o_w, o_b, f1_w, f1_b, ff_w, ff_b,
                                      v_w, pre);

    // ---- embedding branch (bf16 MFMA) ----
    emb_mfma<<<dim3(NB / 64, 16), 256, 0, stream>>>(smiles, emb_w1, emb_b1,
                                                    pre + 576, epart);

    // ---- GCN branch ----
    agg_plain4<<<NNODES / 16, 256, 0, stream>>>(node_x, offs, csr, dinv, buf);
    gemm_dot<<<NNODES / 64, 256, 0, stream>>>(buf, g1_w, g1_b, pre + 512,
                                              dinv, td);
    agg_scalar<<<NNODES / 256, 256, 0, stream>>>(td, offs, csr, dinv, zbuf);
    pool_dot<<<NB / 4, 256, 0, stream>>>(zbuf, startg, cntinv, gpart);

    // ---- combine ----
    final_combine<<<NB / 256, 256, 0, stream>>>(epart, gpart, pre, out);
}

// Round 13
// 436.057 us; speedup vs baseline: 1.7020x; 1.0816x over previous
//
#include <hip/hip_runtime.h>

#define NNODES 262144
#define NEDGES 1048576
#define NB     4096

typedef __attribute__((ext_vector_type(8))) short short8v;   // 8 bf16 (4 VGPRs)
typedef __attribute__((ext_vector_type(4))) float f32x4;     // MFMA acc

__device__ __forceinline__ unsigned short f2bf(float f) {    // RNE float->bf16
    unsigned int u = __float_as_uint(f);
    u += 0x7FFFu + ((u >> 16) & 1u);
    return (unsigned short)(u >> 16);
}
__device__ __forceinline__ float bf2f(unsigned short h) {
    return __uint_as_float((unsigned int)h << 16);
}

// ---------------------------------------------------------------------------
// Embedding branch via bf16 MFMA, fused with v1-dot (unchanged from r10):
// epart[m, by] = sum_j relu(smiles[m]@W1[:,j]+b1[j]) * v1[j]
// ---------------------------------------------------------------------------
__global__ __launch_bounds__(256) void emb_mfma(
    const float* __restrict__ A, const float* __restrict__ B,
    const float* __restrict__ bias, const float* __restrict__ v1,
    float* __restrict__ epart)
{
    __shared__ __align__(16) unsigned short Asb[64][80];
    __shared__ __align__(16) unsigned short Btb[64][80];
    __shared__ float red[64][16];
    const int tid = threadIdx.x;
    const int w = tid >> 6, lane = tid & 63;
    const int m0 = blockIdx.x * 64, n0 = blockIdx.y * 64;

    f32x4 acc[4] = {{0.f,0.f,0.f,0.f},{0.f,0.f,0.f,0.f},
                    {0.f,0.f,0.f,0.f},{0.f,0.f,0.f,0.f}};

    const int ar = tid >> 2, ak4 = (tid & 3) * 4;
    const int bk = tid >> 2, bc4 = (tid & 3) * 4;

    for (int k0 = 0; k0 < 768; k0 += 64) {
        __syncthreads();
        {
            const float* src = A + (size_t)(m0 + ar) * 768 + k0 + ak4;
#pragma unroll
            for (int rep = 0; rep < 4; ++rep) {
                float4 v = *(const float4*)(src + rep * 16);
                unsigned long long pk =
                      (unsigned long long)f2bf(v.x)
                    | ((unsigned long long)f2bf(v.y) << 16)
                    | ((unsigned long long)f2bf(v.z) << 32)
                    | ((unsigned long long)f2bf(v.w) << 48);
                *(unsigned long long*)&Asb[ar][ak4 + rep * 16] = pk;
            }
        }
        {
            const float* src = B + (size_t)(k0 + bk) * 1024 + n0 + bc4;
#pragma unroll
            for (int rep = 0; rep < 4; ++rep) {
                float4 v = *(const float4*)(src + rep * 16);
                Btb[bc4 + rep * 16 + 0][bk] = f2bf(v.x);
                Btb[bc4 + rep * 16 + 1][bk] = f2bf(v.y);
                Btb[bc4 + rep * 16 + 2][bk] = f2bf(v.z);
                Btb[bc4 + rep * 16 + 3][bk] = f2bf(v.w);
            }
        }
        __syncthreads();
#pragma unroll
        for (int ks = 0; ks < 2; ++ks) {
            short8v af = *(const short8v*)&Asb[w * 16 + (lane & 15)][ks * 32 + 8 * (lane >> 4)];
#pragma unroll
            for (int ct = 0; ct < 4; ++ct) {
                short8v bf = *(const short8v*)&Btb[ct * 16 + (lane & 15)][ks * 32 + 8 * (lane >> 4)];
                acc[ct] = __builtin_amdgcn_mfma_f32_16x16x32_bf16(af, bf, acc[ct], 0, 0, 0);
            }
        }
    }

    float p[4] = {0.f, 0.f, 0.f, 0.f};
#pragma unroll
    for (int ct = 0; ct < 4; ++ct) {
        const int col = n0 + ct * 16 + (lane & 15);
        const float bcv = bias[col], vcv = v1[col];
#pragma unroll
        for (int i = 0; i < 4; ++i)
            p[i] += fmaxf(acc[ct][i] + bcv, 0.f) * vcv;
    }
#pragma unroll
    for (int i = 0; i < 4; ++i)
        red[w * 16 + 4 * (lane >> 4) + i][lane & 15] = p[i];
    __syncthreads();
    if (tid < 64) {
        float s = 0.f;
#pragma unroll
        for (int c = 0; c < 16; ++c) s += red[tid][c];
        epart[(size_t)(m0 + tid) * 16 + blockIdx.y] = s;
    }
}

// ---------------------------------------------------------------------------
// Ys[i,:] = bf16( dinv[i] * (node_x @ g1_w)[i,:] )   -- 32 MB bf16 table.
// (A_hat X)W = A_hat (XW): W applied BEFORE aggregation; dinv_s folded in.
// ---------------------------------------------------------------------------
__global__ __launch_bounds__(256) void gemm_y(
    const float* __restrict__ A, const float* __restrict__ B,
    const float* __restrict__ dinv, unsigned short* __restrict__ Ys)
{
    __shared__ float As[16][64];
    __shared__ float Bs[16][64];
    const int tid = threadIdx.x;
    const int tx = tid & 15, ty = tid >> 4;
    const int m0 = blockIdx.x * 64;

    float acc[4][4] = {};
    const int ar = tid >> 2, aseg = tid & 3;
    const int bk = tid >> 4, bseg = tid & 15;
    const float* Aptr = A + (size_t)(m0 + ar) * 64 + aseg * 4;
    const float* Bptr = B + (size_t)bk * 64 + bseg * 4;

    for (int k0 = 0; k0 < 64; k0 += 16) {
        float4 av = *(const float4*)(Aptr + k0);
        float4 bv = *(const float4*)(Bptr + (size_t)k0 * 64);
        __syncthreads();
        As[aseg * 4 + 0][ar] = av.x;
        As[aseg * 4 + 1][ar] = av.y;
        As[aseg * 4 + 2][ar] = av.z;
        As[aseg * 4 + 3][ar] = av.w;
        *(float4*)&Bs[bk][bseg * 4] = bv;
        __syncthreads();
#pragma unroll
        for (int k = 0; k < 16; ++k) {
            float4 a4 = *(const float4*)&As[k][ty * 4];
            float4 b4 = *(const float4*)&Bs[k][tx * 4];
            float aa[4] = {a4.x, a4.y, a4.z, a4.w};
            float bb[4] = {b4.x, b4.y, b4.z, b4.w};
#pragma unroll
            for (int i = 0; i < 4; ++i)
#pragma unroll
                for (int j = 0; j < 4; ++j)
                    acc[i][j] += aa[i] * bb[j];
        }
    }

#pragma unroll
    for (int i = 0; i < 4; ++i) {
        const int row = m0 + ty * 4 + i;
        const float dv = dinv[row];
        unsigned short h4[4];
#pragma unroll
        for (int j = 0; j < 4; ++j) h4[j] = f2bf(acc[i][j] * dv);
        *(unsigned long long*)&Ys[(size_t)row * 64 + tx * 4] =
              (unsigned long long)h4[0]
            | ((unsigned long long)h4[1] << 16)
            | ((unsigned long long)h4[2] << 32)
            | ((unsigned long long)h4[3] << 48);
    }
}

// ---------------------------------------------------------------------------
// CSR build
// ---------------------------------------------------------------------------
__global__ void count_deg(const int* __restrict__ dst, int* __restrict__ deg)
{
    int i = blockIdx.x * 256 + threadIdx.x;
    if (i < NEDGES) atomicAdd(&deg[dst[i]], 1);
}

__global__ void make_dinv(const int* __restrict__ deg, float* __restrict__ dinv)
{
    int i = blockIdx.x * 256 + threadIdx.x;
    if (i < NNODES) dinv[i] = rsqrtf((float)(deg[i] + 1));   // +1 self loop
}

__global__ __launch_bounds__(1024) void scan_block(
    const int* __restrict__ in, int* __restrict__ out, int* __restrict__ bsums)
{
    __shared__ int tmp[1024];
    const int tid = threadIdx.x;
    const int gid = blockIdx.x * 1024 + tid;
    int v = in[gid];
    tmp[tid] = v;
    __syncthreads();
    for (int off = 1; off < 1024; off <<= 1) {
        int t = (tid >= off) ? tmp[tid - off] : 0;
        __syncthreads();
        tmp[tid] += t;
        __syncthreads();
    }
    out[gid] = tmp[tid] - v;                 // exclusive
    if (tid == 1023) bsums[blockIdx.x] = tmp[tid];
}

__global__ __launch_bounds__(256) void scan_top(int* __restrict__ bsums)
{
    __shared__ int tmp[256];
    const int tid = threadIdx.x;
    int v = bsums[tid];
    tmp[tid] = v;
    __syncthreads();
    for (int off = 1; off < 256; off <<= 1) {
        int t = (tid >= off) ? tmp[tid - off] : 0;
        __syncthreads();
        tmp[tid] += t;
        __syncthreads();
    }
    bsums[tid] = tmp[tid] - v;
}

__global__ void scan_add(int* __restrict__ out, const int* __restrict__ bsums)
{
    int gid = blockIdx.x * 256 + threadIdx.x;
    out[gid] += bsums[gid >> 10];
}

__global__ void scatter_edges(const int* __restrict__ src, const int* __restrict__ dst,
                              int* __restrict__ cur, int* __restrict__ csr)
{
    int i = blockIdx.x * 256 + threadIdx.x;
    if (i < NEDGES) {
        int d = dst[i];
        int pos = atomicAdd(&cur[d], 1);
        csr[pos] = src[i];
    }
}

// ---------------------------------------------------------------------------
// Fused layer-1 aggregation + relu-dot (merges old agg_plain4 + gemm_dot):
// agg_i[lane] = dinv_i*(Ys[i,lane] + sum_{s in N(i)} Ys[s,lane])
// td[i] = dinv_i * sum_lane relu(agg_i[lane] + g1_b[lane]) * v2[lane]
// Wave per 4 consecutive nodes; 128B bf16 row gathers; 8-deep unroll.
// ---------------------------------------------------------------------------
__global__ __launch_bounds__(256) void agg_dot(
    const unsigned short* __restrict__ Ys, const int* __restrict__ offs,
    const int* __restrict__ csr, const float* __restrict__ dinv,
    const float* __restrict__ g1_b, const float* __restrict__ v2,
    float* __restrict__ td)
{
    const int q = (blockIdx.x * 256 + threadIdx.x) >> 6;
    const int lane = threadIdx.x & 63;
    const int n0 = q * 4;
    if (n0 >= NNODES) return;

    const int o0 = offs[n0];
    const int o1 = offs[n0 + 1];
    const int o2 = offs[n0 + 2];
    const int o3 = offs[n0 + 3];
    const int o4 = (n0 + 4 < NNODES) ? offs[n0 + 4] : NEDGES;

    float a0 = bf2f(Ys[(size_t)(n0 + 0) * 64 + lane]);
    float a1 = bf2f(Ys[(size_t)(n0 + 1) * 64 + lane]);
    float a2 = bf2f(Ys[(size_t)(n0 + 2) * 64 + lane]);
    float a3 = bf2f(Ys[(size_t)(n0 + 3) * 64 + lane]);

    int e = o0;
    for (; e + 8 <= o4; e += 8) {
        int s[8];
#pragma unroll
        for (int u = 0; u < 8; ++u) s[u] = csr[e + u];
        float hv[8];
#pragma unroll
        for (int u = 0; u < 8; ++u) hv[u] = bf2f(Ys[(size_t)s[u] * 64 + lane]);
#pragma unroll
        for (int u = 0; u < 8; ++u) {
            const int ei = e + u;               // wave-uniform branch
            if      (ei < o1) a0 += hv[u];
            else if (ei < o2) a1 += hv[u];
            else if (ei < o3) a2 += hv[u];
            else              a3 += hv[u];
        }
    }
    for (; e < o4; ++e) {
        const float c = bf2f(Ys[(size_t)csr[e] * 64 + lane]);
        if      (e < o1) a0 += c;
        else if (e < o2) a1 += c;
        else if (e < o3) a2 += c;
        else             a3 += c;
    }

    const float bb = g1_b[lane], vv = v2[lane];
    float t0 = fmaxf(a0 * dinv[n0 + 0] + bb, 0.f) * vv;
    float t1 = fmaxf(a1 * dinv[n0 + 1] + bb, 0.f) * vv;
    float t2 = fmaxf(a2 * dinv[n0 + 2] + bb, 0.f) * vv;
    float t3 = fmaxf(a3 * dinv[n0 + 3] + bb, 0.f) * vv;
#pragma unroll
    for (int off = 32; off; off >>= 1) {
        t0 += __shfl_down(t0, off, 64);
        t1 += __shfl_down(t1, off, 64);
        t2 += __shfl_down(t2, off, 64);
        t3 += __shfl_down(t3, off, 64);
    }
    if (lane == 0) {
        td[n0 + 0] = t0 * dinv[n0 + 0];
        td[n0 + 1] = t1 * dinv[n0 + 1];
        td[n0 + 2] = t2 * dinv[n0 + 2];
        td[n0 + 3] = t3 * dinv[n0 + 3];
    }
}

// ---------------------------------------------------------------------------
// Scalar aggregation (layer 2 folded to width 1): thread per node.
// ---------------------------------------------------------------------------
__global__ void agg_scalar(
    const float* __restrict__ td, const int* __restrict__ offs,
    const int* __restrict__ csr, const float* __restrict__ dinv,
    float* __restrict__ z)
{
    int i = blockIdx.x * 256 + threadIdx.x;
    if (i >= NNODES) return;
    float s = td[i];
    const int e0 = offs[i];
    const int e1 = (i + 1 < NNODES) ? offs[i + 1] : NEDGES;
    for (int e = e0; e < e1; ++e) s += td[csr[e]];
    z[i] = s * dinv[i];
}

// Segment mean of z per graph (sorted batch_vec -> contiguous, coalesced).
__global__ __launch_bounds__(256) void pool_dot(
    const float* __restrict__ z, const int* __restrict__ start,
    const float* __restrict__ cntinv, float* __restrict__ gpart)
{
    const int g = (blockIdx.x * 256 + threadIdx.x) >> 6;
    const int lane = threadIdx.x & 63;
    if (g >= NB) return;
    const int s0 = start[g], s1 = start[g + 1];
    float a = 0.f;
    for (int i = s0 + lane; i < s1; i += 64) a += z[i];
#pragma unroll
    for (int off = 32; off; off >>= 1) a += __shfl_down(a, off, 64);
    if (lane == 0) gpart[g] = a * cntinv[g];
}

// ---------------------------------------------------------------------------
// Graph segment boundaries + inverse counts
// ---------------------------------------------------------------------------
__global__ void graph_starts(const int* __restrict__ bv, int* __restrict__ start)
{
    int g = blockIdx.x * 256 + threadIdx.x;
    if (g > NB) return;
    if (g == NB) { start[g] = NNODES; return; }
    int lo = 0, hi = NNODES;
    while (lo < hi) {
        int mid = (lo + hi) >> 1;
        if (bv[mid] < g) lo = mid + 1; else hi = mid;
    }
    start[g] = lo;
}

__global__ void make_cntinv(const int* __restrict__ start, float* __restrict__ cntinv)
{
    int g = blockIdx.x * 256 + threadIdx.x;
    if (g < NB) cntinv[g] = 1.0f / fmaxf((float)(start[g + 1] - start[g]), 1.0f);
}

// ---------------------------------------------------------------------------
// Precompute folded weight vectors (tail is affine).
// pre layout (floats): [0:128) p1, [128:256) p2, [256:384) wfinal,
//                      [384:512) q1, [512:576) v2, [576:1600) v1, [1600] c0
// ---------------------------------------------------------------------------
__global__ __launch_bounds__(256) void precompute(
    const float* __restrict__ emb_w2, const float* __restrict__ emb_b2,
    const float* __restrict__ g2_w, const float* __restrict__ g2_b,
    const float* __restrict__ gfc_w, const float* __restrict__ gfc_b,
    const float* __restrict__ v_b,
    const float* __restrict__ o_w, const float* __restrict__ o_b,
    const float* __restrict__ f1_w, const float* __restrict__ f1_b,
    const float* __restrict__ ff_w, const float* __restrict__ ff_b,
    const float* __restrict__ v_w, float* __restrict__ pre)
{
    const int tid = threadIdx.x;
    float* p1 = pre;           // [128]
    float* p2 = pre + 128;     // [128]
    float* wf = pre + 256;     // [128]
    float* q1 = pre + 384;     // [128]
    float* v2 = pre + 512;     // [64]
    float* v1 = pre + 576;     // [1024]

    if (tid < 128) {                         // p1 = f1_w @ ff_w
        float s = 0.f;
        for (int k = 0; k < 64; ++k) s += f1_w[tid * 64 + k] * ff_w[k];
        p1[tid] = s;
    }
    __syncthreads();
    if (tid < 128) {                         // p2 = o_w @ p1
        float s = 0.f;
        for (int k = 0; k < 128; ++k) s += o_w[tid * 128 + k] * p1[k];
        p2[tid] = s;
    }
    __syncthreads();
    if (tid < 128) {                         // wfinal = v_w @ p2
        float s = 0.f;
        for (int k = 0; k < 128; ++k) s += v_w[tid * 128 + k] * p2[k];
        wf[tid] = s;
    }
    __syncthreads();
    if (tid < 128) {                         // q1 = gfc_w @ wf2
        float s = 0.f;
        for (int k = 0; k < 64; ++k) s += gfc_w[tid * 64 + k] * wf[64 + k];
        q1[tid] = s;
    }
    __syncthreads();
    if (tid < 64) {                          // v2 = g2_w @ q1
        float s = 0.f;
        for (int k = 0; k < 128; ++k) s += g2_w[tid * 128 + k] * q1[k];
        v2[tid] = s;
    }
    for (int r = 0; r < 4; ++r) {            // v1 = emb_w2 @ wf1
        int j = tid + 256 * r;
        float s = 0.f;
        for (int k = 0; k < 64; ++k) s += emb_w2[j * 64 + k] * wf[k];
        v1[j] = s;
    }
    if (tid == 0) {                          // c0 (all bias-chain dots)
        float c = ff_b[0];
        for (int k = 0; k < 64; ++k)  c += f1_b[k] * ff_w[k];
        for (int i = 0; i < 128; ++i) c += o_b[i] * p1[i] + v_b[i] * p2[i];
        for (int k = 0; k < 64; ++k)  c += emb_b2[k] * wf[k];
        for (int i = 0; i < 128; ++i) c += g2_b[i] * q1[i];
        for (int k = 0; k < 64; ++k)  c += gfc_b[k] * wf[64 + k];
        pre[1600] = c;
    }
}

// out[b] = sum_c epart[b,c] + gpart[b] + c0
__global__ void final_combine(
    const float* __restrict__ epart, const float* __restrict__ gpart,
    const float* __restrict__ pre, float* __restrict__ out)
{
    int b = blockIdx.x * 256 + threadIdx.x;
    if (b >= NB) return;
    float s = pre[1600] + gpart[b];
    const float* ep = &epart[(size_t)b * 16];
#pragma unroll
    for (int c = 0; c < 16; ++c) s += ep[c];
    out[b] = s;
}

// ---------------------------------------------------------------------------
extern "C" void kernel_launch(void* const* d_in, const int* in_sizes, int n_in,
                              void* d_out, int out_size, void* d_ws, size_t ws_size,
                              hipStream_t stream)
{
    const float* smiles = (const float*)d_in[0];    // [4096,1,768]
    const float* node_x = (const float*)d_in[1];    // [262144,64]
    const int*   esrc   = (const int*)d_in[2];
    const int*   edst   = (const int*)d_in[3];
    const int*   bvec   = (const int*)d_in[4];      // sorted
    const float* emb_w1 = (const float*)d_in[5];    // [768,1024]
    const float* emb_b1 = (const float*)d_in[6];
    const float* emb_w2 = (const float*)d_in[7];    // [1024,64]
    const float* emb_b2 = (const float*)d_in[8];
    const float* g1_w   = (const float*)d_in[9];    // [64,64]
    const float* g1_b   = (const float*)d_in[10];
    const float* g2_w   = (const float*)d_in[11];   // [64,128]
    const float* g2_b   = (const float*)d_in[12];
    const float* gfc_w  = (const float*)d_in[13];   // [128,64]
    const float* gfc_b  = (const float*)d_in[14];
    // q_w/q_b/k_w/k_b (15..18) dead: S=1 collapses top-k softmax to identity
    const float* v_w    = (const float*)d_in[19];   // [128,128]
    const float* v_b    = (const float*)d_in[20];
    const float* o_w    = (const float*)d_in[21];   // [128,128]
    const float* o_b    = (const float*)d_in[22];
    const float* f1_w   = (const float*)d_in[23];   // [128,64]
    const float* f1_b   = (const float*)d_in[24];
    const float* ff_w   = (const float*)d_in[25];   // [64,1]
    const float* ff_b   = (const float*)d_in[26];   // [1]
    float* out = (float*)d_out;

    // workspace carve-up (total ~45 MB)
    char* ws = (char*)d_ws;
    size_t off = 0;
    auto alloc = [&](size_t b) -> void* {
        void* p = ws + off;
        off += (b + 255) & ~(size_t)255;
        return p;
    };
    unsigned short* Ys = (unsigned short*)alloc((size_t)NNODES * 64 * 2); // 32 MB bf16
    int*   deg    = (int*)alloc((size_t)NNODES * 4);
    int*   offs   = (int*)alloc((size_t)NNODES * 4);
    int*   cur    = (int*)alloc((size_t)NNODES * 4);
    float* dinv   = (float*)alloc((size_t)NNODES * 4);
    int*   csr    = (int*)alloc((size_t)NEDGES * 4);
    int*   startg = (int*)alloc((size_t)(NB + 1) * 4);
    int*   bsums  = (int*)alloc(256 * 4);
    float* cntinv = (float*)alloc((size_t)NB * 4);
    float* epart  = (float*)alloc((size_t)NB * 16 * 4);
    float* td     = (float*)alloc((size_t)NNODES * 4);
    float* zbuf   = (float*)alloc((size_t)NNODES * 4);
    float* gpart  = (float*)alloc((size_t)NB * 4);
    float* pre    = (float*)alloc(2048 * 4);

    // ---- CSR build (int atomics only) ----
    hipMemsetAsync(deg, 0, (size_t)NNODES * 4, stream);
    count_deg<<<NEDGES / 256, 256, 0, stream>>>(edst, deg);
    make_dinv<<<NNODES / 256, 256, 0, stream>>>(deg, dinv);
    scan_block<<<NNODES / 1024, 1024, 0, stream>>>(deg, offs, bsums);
    scan_top<<<1, 256, 0, stream>>>(bsums);
    scan_add<<<NNODES / 256, 256, 0, stream>>>(offs, bsums);
    hipMemcpyAsync(cur, offs, (size_t)NNODES * 4, hipMemcpyDeviceToDevice, stream);
    scatter_edges<<<NEDGES / 256, 256, 0, stream>>>(esrc, edst, cur, csr);
    graph_starts<<<(NB + 256) / 256, 256, 0, stream>>>(bvec, startg);
    make_cntinv<<<NB / 256, 256, 0, stream>>>(startg, cntinv);

    // ---- folded tail weights ----
    precompute<<<1, 256, 0, stream>>>(emb_w2, emb_b2, g2_w, g2_b, gfc_w, gfc_b,
                                      v_b, o_w, o_b, f1_w, f1_b, ff_w, ff_b,
                                      v_w, pre);

    // ---- embedding branch (bf16 MFMA) ----
    emb_mfma<<<dim3(NB / 64, 16), 256, 0, stream>>>(smiles, emb_w1, emb_b1,
                                                    pre + 576, epart);

    // ---- GCN branch: W-first + dinv folded into bf16 table, then fused agg ----
    gemm_y<<<NNODES / 64, 256, 0, stream>>>(node_x, g1_w, dinv, Ys);
    agg_dot<<<NNODES / 16, 256, 0, stream>>>(Ys, offs, csr, dinv,
                                             g1_b, pre + 512, td);
    agg_scalar<<<NNODES / 256, 256, 0, stream>>>(td, offs, csr, dinv, zbuf);
    pool_dot<<<NB / 4, 256, 0, stream>>>(zbuf, startg, cntinv, gpart);

    // ---- combine ----
    final_combine<<<NB / 256, 256, 0, stream>>>(epart, gpart, pre, out);
}

// Round 14
// 364.771 us; speedup vs baseline: 2.0346x; 1.1954x over previous
//
#include <hip/hip_runtime.h>

#define NNODES 262144
#define NEDGES 1048576
#define NB     4096
#define NBUCK  512      // dst>>9 -> bucket of 512 nodes
#define BSHIFT 9
#define NBLK_A 256      // blocks in hist/part phases
#define CHUNK  4096     // edges per block in hist/part

typedef __attribute__((ext_vector_type(8))) short short8v;   // 8 bf16 (4 VGPRs)
typedef __attribute__((ext_vector_type(4))) float f32x4;     // MFMA acc

__device__ __forceinline__ unsigned short f2bf(float f) {    // RNE float->bf16
    unsigned int u = __float_as_uint(f);
    u += 0x7FFFu + ((u >> 16) & 1u);
    return (unsigned short)(u >> 16);
}
__device__ __forceinline__ float bf2f(unsigned short h) {
    return __uint_as_float((unsigned int)h << 16);
}

// ---------------------------------------------------------------------------
// Embedding branch via bf16 MFMA, fused with v1-dot (unchanged):
// ---------------------------------------------------------------------------
__global__ __launch_bounds__(256) void emb_mfma(
    const float* __restrict__ A, const float* __restrict__ B,
    const float* __restrict__ bias, const float* __restrict__ v1,
    float* __restrict__ epart)
{
    __shared__ __align__(16) unsigned short Asb[64][80];
    __shared__ __align__(16) unsigned short Btb[64][80];
    __shared__ float red[64][16];
    const int tid = threadIdx.x;
    const int w = tid >> 6, lane = tid & 63;
    const int m0 = blockIdx.x * 64, n0 = blockIdx.y * 64;

    f32x4 acc[4] = {{0.f,0.f,0.f,0.f},{0.f,0.f,0.f,0.f},
                    {0.f,0.f,0.f,0.f},{0.f,0.f,0.f,0.f}};

    const int ar = tid >> 2, ak4 = (tid & 3) * 4;
    const int bk = tid >> 2, bc4 = (tid & 3) * 4;

    for (int k0 = 0; k0 < 768; k0 += 64) {
        __syncthreads();
        {
            const float* src = A + (size_t)(m0 + ar) * 768 + k0 + ak4;
#pragma unroll
            for (int rep = 0; rep < 4; ++rep) {
                float4 v = *(const float4*)(src + rep * 16);
                unsigned long long pk =
                      (unsigned long long)f2bf(v.x)
                    | ((unsigned long long)f2bf(v.y) << 16)
                    | ((unsigned long long)f2bf(v.z) << 32)
                    | ((unsigned long long)f2bf(v.w) << 48);
                *(unsigned long long*)&Asb[ar][ak4 + rep * 16] = pk;
            }
        }
        {
            const float* src = B + (size_t)(k0 + bk) * 1024 + n0 + bc4;
#pragma unroll
            for (int rep = 0; rep < 4; ++rep) {
                float4 v = *(const float4*)(src + rep * 16);
                Btb[bc4 + rep * 16 + 0][bk] = f2bf(v.x);
                Btb[bc4 + rep * 16 + 1][bk] = f2bf(v.y);
                Btb[bc4 + rep * 16 + 2][bk] = f2bf(v.z);
                Btb[bc4 + rep * 16 + 3][bk] = f2bf(v.w);
            }
        }
        __syncthreads();
#pragma unroll
        for (int ks = 0; ks < 2; ++ks) {
            short8v af = *(const short8v*)&Asb[w * 16 + (lane & 15)][ks * 32 + 8 * (lane >> 4)];
#pragma unroll
            for (int ct = 0; ct < 4; ++ct) {
                short8v bf = *(const short8v*)&Btb[ct * 16 + (lane & 15)][ks * 32 + 8 * (lane >> 4)];
                acc[ct] = __builtin_amdgcn_mfma_f32_16x16x32_bf16(af, bf, acc[ct], 0, 0, 0);
            }
        }
    }

    float p[4] = {0.f, 0.f, 0.f, 0.f};
#pragma unroll
    for (int ct = 0; ct < 4; ++ct) {
        const int col = n0 + ct * 16 + (lane & 15);
        const float bcv = bias[col], vcv = v1[col];
#pragma unroll
        for (int i = 0; i < 4; ++i)
            p[i] += fmaxf(acc[ct][i] + bcv, 0.f) * vcv;
    }
#pragma unroll
    for (int i = 0; i < 4; ++i)
        red[w * 16 + 4 * (lane >> 4) + i][lane & 15] = p[i];
    __syncthreads();
    if (tid < 64) {
        float s = 0.f;
#pragma unroll
        for (int c = 0; c < 16; ++c) s += red[tid][c];
        epart[(size_t)(m0 + tid) * 16 + blockIdx.y] = s;
    }
}

// ---------------------------------------------------------------------------
// Ys[i,:] = bf16( dinv[i] * (node_x @ g1_w)[i,:] )   (unchanged)
// ---------------------------------------------------------------------------
__global__ __launch_bounds__(256) void gemm_y(
    const float* __restrict__ A, const float* __restrict__ B,
    const float* __restrict__ dinv, unsigned short* __restrict__ Ys)
{
    __shared__ float As[16][64];
    __shared__ float Bs[16][64];
    const int tid = threadIdx.x;
    const int tx = tid & 15, ty = tid >> 4;
    const int m0 = blockIdx.x * 64;

    float acc[4][4] = {};
    const int ar = tid >> 2, aseg = tid & 3;
    const int bk = tid >> 4, bseg = tid & 15;
    const float* Aptr = A + (size_t)(m0 + ar) * 64 + aseg * 4;
    const float* Bptr = B + (size_t)bk * 64 + bseg * 4;

    for (int k0 = 0; k0 < 64; k0 += 16) {
        float4 av = *(const float4*)(Aptr + k0);
        float4 bv = *(const float4*)(Bptr + (size_t)k0 * 64);
        __syncthreads();
        As[aseg * 4 + 0][ar] = av.x;
        As[aseg * 4 + 1][ar] = av.y;
        As[aseg * 4 + 2][ar] = av.z;
        As[aseg * 4 + 3][ar] = av.w;
        *(float4*)&Bs[bk][bseg * 4] = bv;
        __syncthreads();
#pragma unroll
        for (int k = 0; k < 16; ++k) {
            float4 a4 = *(const float4*)&As[k][ty * 4];
            float4 b4 = *(const float4*)&Bs[k][tx * 4];
            float aa[4] = {a4.x, a4.y, a4.z, a4.w};
            float bb[4] = {b4.x, b4.y, b4.z, b4.w};
#pragma unroll
            for (int i = 0; i < 4; ++i)
#pragma unroll
                for (int j = 0; j < 4; ++j)
                    acc[i][j] += aa[i] * bb[j];
        }
    }

#pragma unroll
    for (int i = 0; i < 4; ++i) {
        const int row = m0 + ty * 4 + i;
        const float dv = dinv[row];
        unsigned short h4[4];
#pragma unroll
        for (int j = 0; j < 4; ++j) h4[j] = f2bf(acc[i][j] * dv);
        *(unsigned long long*)&Ys[(size_t)row * 64 + tx * 4] =
              (unsigned long long)h4[0]
            | ((unsigned long long)h4[1] << 16)
            | ((unsigned long long)h4[2] << 32)
            | ((unsigned long long)h4[3] << 48);
    }
}

// ---------------------------------------------------------------------------
// Locality-partitioned CSR build: all per-edge atomics in LDS,
// all global writes coalesced or confined to small contiguous windows.
// ---------------------------------------------------------------------------
// Phase A: per-block bucket histogram -> bcnt[bucket*NBLK_A + blk]
__global__ __launch_bounds__(256) void bucket_hist(
    const int* __restrict__ dst, int* __restrict__ bcnt)
{
    __shared__ int hist[NBUCK];
    const int tid = threadIdx.x, blk = blockIdx.x;
    for (int i = tid; i < NBUCK; i += 256) hist[i] = 0;
    __syncthreads();
    const int e0 = blk * CHUNK;
    for (int i = tid; i < CHUNK; i += 256)
        atomicAdd(&hist[dst[e0 + i] >> BSHIFT], 1);
    __syncthreads();
    for (int i = tid; i < NBUCK; i += 256)
        bcnt[i * NBLK_A + blk] = hist[i];
}

// Phase B: partition edges into bucket-major staging pairs (dst<<32 | src)
__global__ __launch_bounds__(256) void bucket_part(
    const int* __restrict__ src, const int* __restrict__ dst,
    const int* __restrict__ bpos, unsigned long long* __restrict__ pairs)
{
    __shared__ int cur[NBUCK];
    const int tid = threadIdx.x, blk = blockIdx.x;
    for (int i = tid; i < NBUCK; i += 256)
        cur[i] = bpos[i * NBLK_A + blk];
    __syncthreads();
    const int e0 = blk * CHUNK;
    for (int i = tid; i < CHUNK; i += 256) {
        const int d = dst[e0 + i], s = src[e0 + i];
        const int pos = atomicAdd(&cur[d >> BSHIFT], 1);
        pairs[pos] = ((unsigned long long)(unsigned int)d << 32) | (unsigned int)s;
    }
}

// Phase C1: per-bucket degree count (no global atomics; exclusive ownership)
__global__ __launch_bounds__(256) void bucket_deg(
    const unsigned long long* __restrict__ pairs, const int* __restrict__ bpos,
    int* __restrict__ deg)
{
    __shared__ int dl[512];
    const int tid = threadIdx.x, b = blockIdx.x;
    dl[tid] = 0; dl[tid + 256] = 0;
    __syncthreads();
    const int s0 = bpos[b * NBLK_A];
    const int s1 = (b + 1 < NBUCK) ? bpos[(b + 1) * NBLK_A] : NEDGES;
    const int base = b << BSHIFT;
    for (int e = s0 + tid; e < s1; e += 256)
        atomicAdd(&dl[(int)(pairs[e] >> 32) - base], 1);
    __syncthreads();
    deg[base + tid] = dl[tid];
    deg[base + tid + 256] = dl[tid + 256];
}

// Phase C2: per-bucket scatter into csr (writes confined to ~8KB window)
__global__ __launch_bounds__(256) void bucket_scatter(
    const unsigned long long* __restrict__ pairs, const int* __restrict__ bpos,
    const int* __restrict__ offs, int* __restrict__ csr)
{
    __shared__ int cl[512];
    const int tid = threadIdx.x, b = blockIdx.x;
    const int base = b << BSHIFT;
    cl[tid] = offs[base + tid];
    cl[tid + 256] = offs[base + tid + 256];
    __syncthreads();
    const int s0 = bpos[b * NBLK_A];
    const int s1 = (b + 1 < NBUCK) ? bpos[(b + 1) * NBLK_A] : NEDGES;
    for (int e = s0 + tid; e < s1; e += 256) {
        const unsigned long long p = pairs[e];
        const int pos = atomicAdd(&cl[(int)(p >> 32) - base], 1);
        csr[pos] = (int)(p & 0xFFFFFFFFull);
    }
}

__global__ void make_dinv(const int* __restrict__ deg, float* __restrict__ dinv)
{
    int i = blockIdx.x * 256 + threadIdx.x;
    if (i < NNODES) dinv[i] = rsqrtf((float)(deg[i] + 1));   // +1 self loop
}

// ---------------------------------------------------------------------------
// Scan machinery (scan_top generalized to n <= 256)
// ---------------------------------------------------------------------------
__global__ __launch_bounds__(1024) void scan_block(
    const int* __restrict__ in, int* __restrict__ out, int* __restrict__ bsums)
{
    __shared__ int tmp[1024];
    const int tid = threadIdx.x;
    const int gid = blockIdx.x * 1024 + tid;
    int v = in[gid];
    tmp[tid] = v;
    __syncthreads();
    for (int off = 1; off < 1024; off <<= 1) {
        int t = (tid >= off) ? tmp[tid - off] : 0;
        __syncthreads();
        tmp[tid] += t;
        __syncthreads();
    }
    out[gid] = tmp[tid] - v;                 // exclusive
    if (tid == 1023) bsums[blockIdx.x] = tmp[tid];
}

__global__ __launch_bounds__(256) void scan_top(int* __restrict__ bsums, int n)
{
    __shared__ int tmp[256];
    const int tid = threadIdx.x;
    int v = (tid < n) ? bsums[tid] : 0;
    tmp[tid] = v;
    __syncthreads();
    for (int off = 1; off < 256; off <<= 1) {
        int t = (tid >= off) ? tmp[tid - off] : 0;
        __syncthreads();
        tmp[tid] += t;
        __syncthreads();
    }
    if (tid < n) bsums[tid] = tmp[tid] - v;
}

__global__ void scan_add(int* __restrict__ out, const int* __restrict__ bsums)
{
    int gid = blockIdx.x * 256 + threadIdx.x;
    out[gid] += bsums[gid >> 10];
}

// ---------------------------------------------------------------------------
// Fused layer-1 aggregation + relu-dot (unchanged from r12)
// ---------------------------------------------------------------------------
__global__ __launch_bounds__(256) void agg_dot(
    const unsigned short* __restrict__ Ys, const int* __restrict__ offs,
    const int* __restrict__ csr, const float* __restrict__ dinv,
    const float* __restrict__ g1_b, const float* __restrict__ v2,
    float* __restrict__ td)
{
    const int q = (blockIdx.x * 256 + threadIdx.x) >> 6;
    const int lane = threadIdx.x & 63;
    const int n0 = q * 4;
    if (n0 >= NNODES) return;

    const int o0 = offs[n0];
    const int o1 = offs[n0 + 1];
    const int o2 = offs[n0 + 2];
    const int o3 = offs[n0 + 3];
    const int o4 = (n0 + 4 < NNODES) ? offs[n0 + 4] : NEDGES;

    float a0 = bf2f(Ys[(size_t)(n0 + 0) * 64 + lane]);
    float a1 = bf2f(Ys[(size_t)(n0 + 1) * 64 + lane]);
    float a2 = bf2f(Ys[(size_t)(n0 + 2) * 64 + lane]);
    float a3 = bf2f(Ys[(size_t)(n0 + 3) * 64 + lane]);

    int e = o0;
    for (; e + 8 <= o4; e += 8) {
        int s[8];
#pragma unroll
        for (int u = 0; u < 8; ++u) s[u] = csr[e + u];
        float hv[8];
#pragma unroll
        for (int u = 0; u < 8; ++u) hv[u] = bf2f(Ys[(size_t)s[u] * 64 + lane]);
#pragma unroll
        for (int u = 0; u < 8; ++u) {
            const int ei = e + u;               // wave-uniform branch
            if      (ei < o1) a0 += hv[u];
            else if (ei < o2) a1 += hv[u];
            else if (ei < o3) a2 += hv[u];
            else              a3 += hv[u];
        }
    }
    for (; e < o4; ++e) {
        const float c = bf2f(Ys[(size_t)csr[e] * 64 + lane]);
        if      (e < o1) a0 += c;
        else if (e < o2) a1 += c;
        else if (e < o3) a2 += c;
        else             a3 += c;
    }

    const float bb = g1_b[lane], vv = v2[lane];
    float t0 = fmaxf(a0 * dinv[n0 + 0] + bb, 0.f) * vv;
    float t1 = fmaxf(a1 * dinv[n0 + 1] + bb, 0.f) * vv;
    float t2 = fmaxf(a2 * dinv[n0 + 2] + bb, 0.f) * vv;
    float t3 = fmaxf(a3 * dinv[n0 + 3] + bb, 0.f) * vv;
#pragma unroll
    for (int off = 32; off; off >>= 1) {
        t0 += __shfl_down(t0, off, 64);
        t1 += __shfl_down(t1, off, 64);
        t2 += __shfl_down(t2, off, 64);
        t3 += __shfl_down(t3, off, 64);
    }
    if (lane == 0) {
        td[n0 + 0] = t0 * dinv[n0 + 0];
        td[n0 + 1] = t1 * dinv[n0 + 1];
        td[n0 + 2] = t2 * dinv[n0 + 2];
        td[n0 + 3] = t3 * dinv[n0 + 3];
    }
}

// ---------------------------------------------------------------------------
// Scalar aggregation (layer 2 folded to width 1): thread per node.
// ---------------------------------------------------------------------------
__global__ void agg_scalar(
    const float* __restrict__ td, const int* __restrict__ offs,
    const int* __restrict__ csr, const float* __restrict__ dinv,
    float* __restrict__ z)
{
    int i = blockIdx.x * 256 + threadIdx.x;
    if (i >= NNODES) return;
    float s = td[i];
    const int e0 = offs[i];
    const int e1 = (i + 1 < NNODES) ? offs[i + 1] : NEDGES;
    for (int e = e0; e < e1; ++e) s += td[csr[e]];
    z[i] = s * dinv[i];
}

// Segment mean of z per graph (sorted batch_vec -> contiguous, coalesced).
__global__ __launch_bounds__(256) void pool_dot(
    const float* __restrict__ z, const int* __restrict__ start,
    const float* __restrict__ cntinv, float* __restrict__ gpart)
{
    const int g = (blockIdx.x * 256 + threadIdx.x) >> 6;
    const int lane = threadIdx.x & 63;
    if (g >= NB) return;
    const int s0 = start[g], s1 = start[g + 1];
    float a = 0.f;
    for (int i = s0 + lane; i < s1; i += 64) a += z[i];
#pragma unroll
    for (int off = 32; off; off >>= 1) a += __shfl_down(a, off, 64);
    if (lane == 0) gpart[g] = a * cntinv[g];
}

// ---------------------------------------------------------------------------
// Graph segment boundaries + inverse counts
// ---------------------------------------------------------------------------
__global__ void graph_starts(const int* __restrict__ bv, int* __restrict__ start)
{
    int g = blockIdx.x * 256 + threadIdx.x;
    if (g > NB) return;
    if (g == NB) { start[g] = NNODES; return; }
    int lo = 0, hi = NNODES;
    while (lo < hi) {
        int mid = (lo + hi) >> 1;
        if (bv[mid] < g) lo = mid + 1; else hi = mid;
    }
    start[g] = lo;
}

__global__ void make_cntinv(const int* __restrict__ start, float* __restrict__ cntinv)
{
    int g = blockIdx.x * 256 + threadIdx.x;
    if (g < NB) cntinv[g] = 1.0f / fmaxf((float)(start[g + 1] - start[g]), 1.0f);
}

// ---------------------------------------------------------------------------
// Precompute folded weight vectors (tail is affine).
// pre layout (floats): [0:128) p1, [128:256) p2, [256:384) wfinal,
//                      [384:512) q1, [512:576) v2, [576:1600) v1, [1600] c0
// ---------------------------------------------------------------------------
__global__ __launch_bounds__(256) void precompute(
    const float* __restrict__ emb_w2, const float* __restrict__ emb_b2,
    const float* __restrict__ g2_w, const float* __restrict__ g2_b,
    const float* __restrict__ gfc_w, const float* __restrict__ gfc_b,
    const float* __restrict__ v_b,
    const float* __restrict__ o_w, const float* __restrict__ o_b,
    const float* __restrict__ f1_w, const float* __restrict__ f1_b,
    const float* __restrict__ ff_w, const float* __restrict__ ff_b,
    const float* __restrict__ v_w, float* __restrict__ pre)
{
    const int tid = threadIdx.x;
    float* p1 = pre;           // [128]
    float* p2 = pre + 128;     // [128]
    float* wf = pre + 256;     // [128]
    float* q1 = pre + 384;     // [128]
    float* v2 = pre + 512;     // [64]
    float* v1 = pre + 576;     // [1024]

    if (tid < 128) {                         // p1 = f1_w @ ff_w
        float s = 0.f;
        for (int k = 0; k < 64; ++k) s += f1_w[tid * 64 + k] * ff_w[k];
        p1[tid] = s;
    }
    __syncthreads();
    if (tid < 128) {                         // p2 = o_w @ p1
        float s = 0.f;
        for (int k = 0; k < 128; ++k) s += o_w[tid * 128 + k] * p1[k];
        p2[tid] = s;
    }
    __syncthreads();
    if (tid < 128) {                         // wfinal = v_w @ p2
        float s = 0.f;
        for (int k = 0; k < 128; ++k) s += v_w[tid * 128 + k] * p2[k];
        wf[tid] = s;
    }
    __syncthreads();
    if (tid < 128) {                         // q1 = gfc_w @ wf2
        float s = 0.f;
        for (int k = 0; k < 64; ++k) s += gfc_w[tid * 64 + k] * wf[64 + k];
        q1[tid] = s;
    }
    __syncthreads();
    if (tid < 64) {                          // v2 = g2_w @ q1
        float s = 0.f;
        for (int k = 0; k < 128; ++k) s += g2_w[tid * 128 + k] * q1[k];
        v2[tid] = s;
    }
    for (int r = 0; r < 4; ++r) {            // v1 = emb_w2 @ wf1
        int j = tid + 256 * r;
        float s = 0.f;
        for (int k = 0; k < 64; ++k) s += emb_w2[j * 64 + k] * wf[k];
        v1[j] = s;
    }
    if (tid == 0) {                          // c0 (all bias-chain dots)
        float c = ff_b[0];
        for (int k = 0; k < 64; ++k)  c += f1_b[k] * ff_w[k];
        for (int i = 0; i < 128; ++i) c += o_b[i] * p1[i] + v_b[i] * p2[i];
        for (int k = 0; k < 64; ++k)  c += emb_b2[k] * wf[k];
        for (int i = 0; i < 128; ++i) c += g2_b[i] * q1[i];
        for (int k = 0; k < 64; ++k)  c += gfc_b[k] * wf[64 + k];
        pre[1600] = c;
    }
}

// out[b] = sum_c epart[b,c] + gpart[b] + c0
__global__ void final_combine(
    const float* __restrict__ epart, const float* __restrict__ gpart,
    const float* __restrict__ pre, float* __restrict__ out)
{
    int b = blockIdx.x * 256 + threadIdx.x;
    if (b >= NB) return;
    float s = pre[1600] + gpart[b];
    const float* ep = &epart[(size_t)b * 16];
#pragma unroll
    for (int c = 0; c < 16; ++c) s += ep[c];
    out[b] = s;
}

// ---------------------------------------------------------------------------
extern "C" void kernel_launch(void* const* d_in, const int* in_sizes, int n_in,
                              void* d_out, int out_size, void* d_ws, size_t ws_size,
                              hipStream_t stream)
{
    const float* smiles = (const float*)d_in[0];    // [4096,1,768]
    const float* node_x = (const float*)d_in[1];    // [262144,64]
    const int*   esrc   = (const int*)d_in[2];
    const int*   edst   = (const int*)d_in[3];
    const int*   bvec   = (const int*)d_in[4];      // sorted
    const float* emb_w1 = (const float*)d_in[5];    // [768,1024]
    const float* emb_b1 = (const float*)d_in[6];
    const float* emb_w2 = (const float*)d_in[7];    // [1024,64]
    const float* emb_b2 = (const float*)d_in[8];
    const float* g1_w   = (const float*)d_in[9];    // [64,64]
    const float* g1_b   = (const float*)d_in[10];
    const float* g2_w   = (const float*)d_in[11];   // [64,128]
    const float* g2_b   = (const float*)d_in[12];
    const float* gfc_w  = (const float*)d_in[13];   // [128,64]
    const float* gfc_b  = (const float*)d_in[14];
    // q_w/q_b/k_w/k_b (15..18) dead: S=1 collapses top-k softmax to identity
    const float* v_w    = (const float*)d_in[19];   // [128,128]
    const float* v_b    = (const float*)d_in[20];
    const float* o_w    = (const float*)d_in[21];   // [128,128]
    const float* o_b    = (const float*)d_in[22];
    const float* f1_w   = (const float*)d_in[23];   // [128,64]
    const float* f1_b   = (const float*)d_in[24];
    const float* ff_w   = (const float*)d_in[25];   // [64,1]
    const float* ff_b   = (const float*)d_in[26];   // [1]
    float* out = (float*)d_out;

    // workspace carve-up (total ~54 MB)
    char* ws = (char*)d_ws;
    size_t off = 0;
    auto alloc = [&](size_t b) -> void* {
        void* p = ws + off;
        off += (b + 255) & ~(size_t)255;
        return p;
    };
    unsigned short* Ys = (unsigned short*)alloc((size_t)NNODES * 64 * 2); // 32 MB bf16
    unsigned long long* pairs = (unsigned long long*)alloc((size_t)NEDGES * 8); // 8 MB
    int*   bcnt   = (int*)alloc((size_t)NBUCK * NBLK_A * 4);              // 512 KB
    int*   bsumsA = (int*)alloc(256 * 4);
    int*   deg    = (int*)alloc((size_t)NNODES * 4);
    int*   offs   = (int*)alloc((size_t)NNODES * 4);
    float* dinv   = (float*)alloc((size_t)NNODES * 4);
    int*   csr    = (int*)alloc((size_t)NEDGES * 4);
    int*   startg = (int*)alloc((size_t)(NB + 1) * 4);
    int*   bsums  = (int*)alloc(256 * 4);
    float* cntinv = (float*)alloc((size_t)NB * 4);
    float* epart  = (float*)alloc((size_t)NB * 16 * 4);
    float* td     = (float*)alloc((size_t)NNODES * 4);
    float* zbuf   = (float*)alloc((size_t)NNODES * 4);
    float* gpart  = (float*)alloc((size_t)NB * 4);
    float* pre    = (float*)alloc(2048 * 4);

    // ---- CSR build: locality-partitioned (LDS atomics only) ----
    bucket_hist<<<NBLK_A, 256, 0, stream>>>(edst, bcnt);
    // exclusive scan of bcnt (NBUCK*NBLK_A = 131072 ints), in place
    scan_block<<<(NBUCK * NBLK_A) / 1024, 1024, 0, stream>>>(bcnt, bcnt, bsumsA);
    scan_top<<<1, 256, 0, stream>>>(bsumsA, (NBUCK * NBLK_A) / 1024);
    scan_add<<<(NBUCK * NBLK_A) / 256, 256, 0, stream>>>(bcnt, bsumsA);
    bucket_part<<<NBLK_A, 256, 0, stream>>>(esrc, edst, bcnt, pairs);
    bucket_deg<<<NBUCK, 256, 0, stream>>>(pairs, bcnt, deg);
    make_dinv<<<NNODES / 256, 256, 0, stream>>>(deg, dinv);
    scan_block<<<NNODES / 1024, 1024, 0, stream>>>(deg, offs, bsums);
    scan_top<<<1, 256, 0, stream>>>(bsums, NNODES / 1024);
    scan_add<<<NNODES / 256, 256, 0, stream>>>(offs, bsums);
    bucket_scatter<<<NBUCK, 256, 0, stream>>>(pairs, bcnt, offs, csr);

    graph_starts<<<(NB + 256) / 256, 256, 0, stream>>>(bvec, startg);
    make_cntinv<<<NB / 256, 256, 0, stream>>>(startg, cntinv);

    // ---- folded tail weights ----
    precompute<<<1, 256, 0, stream>>>(emb_w2, emb_b2, g2_w, g2_b, gfc_w, gfc_b,
                                      v_b, o_w, o_b, f1_w, f1_b, ff_w, ff_b,
                                      v_w, pre);

    // ---- embedding branch (bf16 MFMA) ----
    emb_mfma<<<dim3(NB / 64, 16), 256, 0, stream>>>(smiles, emb_w1, emb_b1,
                                                    pre + 576, epart);

    // ---- GCN branch ----
    gemm_y<<<NNODES / 64, 256, 0, stream>>>(node_x, g1_w, dinv, Ys);
    agg_dot<<<NNODES / 16, 256, 0, stream>>>(Ys, offs, csr, dinv,
                                             g1_b, pre + 512, td);
    agg_scalar<<<NNODES / 256, 256, 0, stream>>>(td, offs, csr, dinv, zbuf);
    pool_dot<<<NB / 4, 256, 0, stream>>>(zbuf, startg, cntinv, gpart);

    // ---- combine ----
    final_combine<<<NB / 256, 256, 0, stream>>>(epart, gpart, pre, out);
}